// Round 17
// baseline (1307.607 us; speedup 1.0000x reference)
//
#include <hip/hip_runtime.h>
#include <cmath>

// ---------------------------------------------------------------------------
// RPN head post-processing -- exact-semantics HIP port, MEGA-FUSED (R17).
//
// R16 PM: total 388us vs 63us top kernel; summing all 12 dispatches gives
// ~220us of kernel time => ~160us of inter-dispatch gaps (~14us/boundary),
// a floor no per-kernel win ever moved. R17: ALL phases in ONE persistent
// kernel (256 blocks x 1024 threads, all co-resident: 68.5KB LDS & ~90 VGPR
// => >=2 blocks/CU capacity), separated by device-scope software barriers
// (atomic counter + threadfence, s_sleep spin). Phase bodies are the proven
// R16 kernels with mechanical remapping only.
// ---------------------------------------------------------------------------

#define NPRE 2000
#define NPOST 1000
#define NBLK 256

static __device__ __forceinline__ unsigned int flipf_dev(float f) {
  unsigned int u = __float_as_uint(f);
  return (u & 0x80000000u) ? ~u : (u | 0x80000000u);
}
static __device__ __forceinline__ float unflipf_dev(unsigned int k) {
  unsigned int u = (k & 0x80000000u) ? (k ^ 0x80000000u) : ~k;
  return __uint_as_float(u);
}
static __device__ __forceinline__ unsigned long long flip64_dev(double d) {
  unsigned long long u = (unsigned long long)__double_as_longlong(d);
  return (u & 0x8000000000000000ull) ? ~u : (u | 0x8000000000000000ull);
}

struct RPNParams {
  const float* cls[5];
  const float* bbox[5];
  const float* anc[5];
  unsigned int* bar;           // [64] barrier counters (zeroed)
  unsigned int* mainCount;     // [10] (zeroed)
  unsigned int* candCount;     // [10] (zeroed)
  unsigned int* hist;          // [70][16384]
  unsigned int* histT;         // [8][16384]
  unsigned int* Bstar;         // [10]
  unsigned long long* mainEK;  // [10][2048]
  unsigned long long* candEK;  // [10][8192]
  unsigned long long* ekG;     // [10][2048]
  unsigned int* partialR;      // [10][8][2048]
  double* selBoxes;            // [10][2000][4]
  double* selScores;           // [10][2000]
  unsigned long long* mask;    // [10][2000][32]
  double* postScores;          // [10][1000]
  float* postBoxes;            // [10][1000][4]
  unsigned int* partial;       // [2][20][5000]
  float* out;                  // [2][1000][4]
};

__device__ __constant__ int c_NL[5]  = {201600, 50400, 12600, 3150, 819};
__device__ __constant__ int c_HW[5]  = {67200, 16800, 4200, 1050, 273};
__device__ __constant__ int c_BPT[8] = {99, 99, 25, 25, 7, 7, 2, 2};
__device__ __constant__ int c_BPT12[8] = {25, 25, 7, 7, 2, 2, 1, 1};
__device__ __constant__ int c_HSTART[8] = {0, 25, 50, 57, 64, 66, 68, 69};

static __device__ __forceinline__ void map_block(int bx, int& t, int& chunk) {
  int start = 0;
  t = 0;
  for (int k = 0; k < 8; k++) {
    if (bx < start + c_BPT[k]) { t = k; break; }
    start += c_BPT[k];
  }
  chunk = bx - start;
}
static __device__ __forceinline__ void map_block12(int bx, int& t, int& chunk) {
  int start = 0;
  t = 0;
  for (int k = 0; k < 8; k++) {
    if (bx < start + c_BPT12[k]) { t = k; break; }
    start += c_BPT12[k];
  }
  chunk = bx - start;
}

// device-scope sense-free barrier: one counter slot per phase
static __device__ __forceinline__ void gbar(unsigned int* bar, int ph) {
  __syncthreads();
  if (threadIdx.x == 0) {
    __threadfence();  // release all prior global writes
    __hip_atomic_fetch_add(&bar[ph], 1u, __ATOMIC_RELEASE,
                           __HIP_MEMORY_SCOPE_AGENT);
    while (__hip_atomic_load(&bar[ph], __ATOMIC_ACQUIRE,
                             __HIP_MEMORY_SCOPE_AGENT) < (unsigned)NBLK)
      __builtin_amdgcn_s_sleep(2);
  }
  __syncthreads();
  __threadfence();  // acquire: refresh this CU's view
}

#define GRP_N 63
#define RING 6

__global__ __launch_bounds__(1024) void k_mega(RPNParams p) {
  __shared__ unsigned long long SMEM8[8768];  // 70144 B union
  __shared__ int g_gsel;
  __shared__ unsigned int g_baseAbove;
  __shared__ int g_ready[GRP_N];
  __shared__ int g_cons;
  __shared__ unsigned long long g_kw[32], g_aw[32], g_bw[32];
  __shared__ unsigned int g_prefA[33], g_prefB[33];

  int bx = blockIdx.x;
  int tid = threadIdx.x;
  int wave = tid >> 6, lane = tid & 63;

  // ---------------- P1: private 14-bit histogram (70 blocks) ----------------
  if (bx < 70) {
    unsigned int* lh = (unsigned int*)SMEM8;  // 16384
    int t, chunk;
    map_block12(bx, t, chunk);
    int l = t >> 1, b = t & 1;
    int N = c_NL[l], HW = c_HW[l];
    const float* cls = p.cls[l] + (size_t)b * 3 * HW;
    for (int i = tid; i < 16384; i += 1024) lh[i] = 0;
    __syncthreads();
    int base = chunk * 8192 + tid;
#pragma unroll
    for (int k = 0; k < 8; k++) {
      int n = base + k * 1024;
      if (n < N) {
        int a = n % 3, hw = n / 3;
        unsigned int key = flipf_dev(cls[a * HW + hw]);
        atomicAdd(&lh[key >> 18], 1u);
      }
    }
    __syncthreads();
    unsigned int* hout = p.hist + (size_t)bx * 16384;
    for (int i = tid; i < 16384; i += 1024) hout[i] = lh[i];
  }
  gbar(p.bar, 0);

  // ---------------- P2: reduce private hists (128 blocks) -------------------
  if (bx < 128) {
    int t = bx >> 4;
    int slice = bx & 15;
    int bin = slice * 1024 + tid;
    int start = c_HSTART[t];
    int bpt = c_BPT12[t];
    unsigned int s0 = 0, s1 = 0, s2 = 0, s3 = 0;
    int bb = 0;
    for (; bb + 4 <= bpt; bb += 4) {
      s0 += p.hist[(size_t)(start + bb + 0) * 16384 + bin];
      s1 += p.hist[(size_t)(start + bb + 1) * 16384 + bin];
      s2 += p.hist[(size_t)(start + bb + 2) * 16384 + bin];
      s3 += p.hist[(size_t)(start + bb + 3) * 16384 + bin];
    }
    for (; bb < bpt; bb++) s0 += p.hist[(size_t)(start + bb) * 16384 + bin];
    p.histT[(size_t)t * 16384 + bin] = s0 + s1 + s2 + s3;
  }
  gbar(p.bar, 1);

  // ---------------- P3: find threshold bucket (8 blocks) --------------------
  if (bx < 8) {
    int t = bx;
    unsigned int* H = (unsigned int*)SMEM8;     // 16384
    unsigned int* S = H + 16384;                // 1024
    const unsigned int* hT = p.histT + (size_t)t * 16384;
    for (int bin = tid; bin < 16384; bin += 1024) H[bin] = hT[bin];
    __syncthreads();
    {
      unsigned int s = 0;
#pragma unroll
      for (int k = 0; k < 16; k++) s += H[tid * 16 + k];
      S[tid] = s;
    }
    __syncthreads();
    for (int off = 1; off < 1024; off <<= 1) {
      unsigned int add = (tid + off < 1024) ? S[tid + off] : 0u;
      __syncthreads();
      S[tid] += add;
      __syncthreads();
    }
    const unsigned int need = NPRE;
    if (S[tid] >= need && (tid == 1023 || S[tid + 1] < need)) {
      g_gsel = tid;
      g_baseAbove = (tid == 1023) ? 0u : S[tid + 1];
    }
    __syncthreads();
    if (tid == 0) {
      int gg = g_gsel;
      unsigned int c = g_baseAbove;
      int bstar = gg * 16;
      for (int bb = 15; bb >= 0; bb--) {
        c += H[gg * 16 + bb];
        if (c >= need) { bstar = gg * 16 + bb; break; }
      }
      p.Bstar[t] = (unsigned int)bstar;
    }
  }
  gbar(p.bar, 2);

  // ---------------- P4: compaction (266 units over 256 blocks) --------------
  for (int u = bx; u < 266; u += NBLK) {
    int t, chunk;
    map_block(u, t, chunk);
    int l = t >> 1, b = t & 1;
    int N = c_NL[l], HW = c_HW[l];
    const float* cls = p.cls[l] + (size_t)b * 3 * HW;
    unsigned int Bs = p.Bstar[t];
    int base = chunk * 2048 + tid;
    for (int k = 0; k < 2; k++) {
      int n = base + k * 1024;
      if (n < N) {
        int a = n % 3, hw = n / 3;
        unsigned int key = flipf_dev(cls[a * HW + hw]);
        unsigned int hi = key >> 18;
        unsigned long long ek =
            ((unsigned long long)key << 32) | (unsigned int)(~(unsigned int)n);
        if (hi > Bs) {
          unsigned int pos = atomicAdd(&p.mainCount[t], 1u);
          if (pos < 2048u) p.mainEK[(size_t)t * 2048 + pos] = ek;
        } else if (hi == Bs) {
          unsigned int pos = atomicAdd(&p.candCount[t], 1u);
          if (pos < 8192u) p.candEK[(size_t)t * 8192 + pos] = ek;
        }
      }
    }
  }
  gbar(p.bar, 3);

  // ---------------- P5: fill ekG (10 blocks, 256 threads, no sync) ----------
  if (bx < 10 && tid < 256) {
    int t = bx;
    int l = t >> 1, b = t & 1;
    int N = c_NL[l], HW = c_HW[l];
    unsigned long long* ekG = p.ekG + (size_t)t * 2048;
    if (N >= NPRE) {
      unsigned int cGT = min(p.mainCount[t], 2000u);
      unsigned int nC = min(p.candCount[t], 8192u);
      unsigned int needIn = 2000u - cGT;
      for (unsigned int m = tid; m < cGT; m += 256)
        ekG[m] = p.mainEK[(size_t)t * 2048 + m];
      const unsigned long long* cek = p.candEK + (size_t)t * 8192;
      for (unsigned int e = tid; e < nC; e += 256) {
        unsigned long long ve = cek[e];
        unsigned int r = 0;
        for (unsigned int j = 0; j < nC; j++) r += (cek[j] > ve) ? 1u : 0u;
        if (r < needIn) ekG[cGT + r] = ve;
      }
      for (unsigned int r2 = 2000u + tid; r2 < 2048u; r2 += 256)
        ekG[r2] = (unsigned long long)(unsigned int)(~r2);
    } else {
      const float* cls = p.cls[l] + (size_t)b * 3 * HW;
      for (int r = tid; r < 2048; r += 256) {
        if (r < N) {
          int a = r % 3, hw = r / 3;
          unsigned int key = flipf_dev(cls[a * HW + hw]);
          ekG[r] = ((unsigned long long)key << 32) |
                   (unsigned int)(~(unsigned int)r);
        } else {
          ekG[r] = (unsigned long long)(unsigned int)(~(unsigned int)r);
        }
      }
    }
  }
  gbar(p.bar, 4);

  // ---------------- P6: sliced counting-rank (80 blocks) --------------------
  if (bx < 80) {
    int t = bx >> 3;
    int s = bx & 7;
    unsigned long long* sl = SMEM8;  // 256
    const unsigned long long* ekG = p.ekG + (size_t)t * 2048;
    if (tid < 256) sl[tid] = ekG[s * 256 + tid];
    __syncthreads();
    if (tid < 256) {
      unsigned long long ve[8];
      unsigned int r[8];
#pragma unroll
      for (int k = 0; k < 8; k++) {
        ve[k] = ekG[k * 256 + tid];
        r[k] = 0;
      }
      for (int j = 0; j < 256; j++) {
        unsigned long long vj = sl[j];
#pragma unroll
        for (int k = 0; k < 8; k++) r[k] += (vj > ve[k]) ? 1u : 0u;
      }
      unsigned int* out = p.partialR + ((size_t)t * 8 + s) * 2048;
#pragma unroll
      for (int k = 0; k < 8; k++) out[k * 256 + tid] = r[k];
    }
  }
  gbar(p.bar, 5);

  // ---------------- P7: scatter + fp64 decode (10 blocks) -------------------
  if (bx < 10) {
    int t = bx;
    int l = t >> 1, b = t & 1;
    int HW = c_HW[l];
    unsigned long long* srt = SMEM8;  // 2048
    const unsigned long long* ekG = p.ekG + (size_t)t * 2048;
    for (int e = tid; e < 2048; e += 1024) {
      unsigned int rk = 0;
#pragma unroll
      for (int s = 0; s < 8; s++)
        rk += p.partialR[((size_t)t * 8 + s) * 2048 + e];
      srt[rk] = ekG[e];
    }
    __syncthreads();
    const double RCLIP = fabs(log(16.0 / 1000.0));
    const float* bbx = p.bbox[l] + (size_t)b * 12 * HW;
    const float* anc = p.anc[l];
    for (int r = tid; r < NPRE; r += 1024) {
      unsigned long long v = srt[r];
      unsigned int key = (unsigned int)(v >> 32);
      double* SB = p.selBoxes + ((size_t)t * NPRE + r) * 4;
      if (key == 0u) {
        SB[0] = 0.0; SB[1] = 0.0; SB[2] = 0.0; SB[3] = 0.0;
        p.selScores[(size_t)t * NPRE + r] = -1.0;
      } else {
        unsigned int idx = ~(unsigned int)(v & 0xFFFFFFFFull);
        int a = (int)(idx % 3u);
        int hw = (int)(idx / 3u);
        double d0 = (double)bbx[(a * 4 + 0) * HW + hw];
        double d1 = (double)bbx[(a * 4 + 1) * HW + hw];
        double d2 = (double)bbx[(a * 4 + 2) * HW + hw];
        double d3 = (double)bbx[(a * 4 + 3) * HW + hw];
        double a0 = (double)anc[(size_t)idx * 4 + 0];
        double a1 = (double)anc[(size_t)idx * 4 + 1];
        double a2 = (double)anc[(size_t)idx * 4 + 2];
        double a3 = (double)anc[(size_t)idx * 4 + 3];
        double dw = fmin(fmax(d2, -RCLIP), RCLIP);
        double dh = fmin(fmax(d3, -RCLIP), RCLIP);
        double pw = a2 - a0, ph = a3 - a1;
        double px = (a0 + a2) * 0.5, py = (a1 + a3) * 0.5;
        double gw = pw * exp(dw), gh = ph * exp(dh);
        double gx = px + pw * d0, gy = py + ph * d1;
        double x1 = fmin(fmax(gx - 0.5 * gw, 0.0), 1344.0);
        double y1 = fmin(fmax(gy - 0.5 * gh, 0.0), 800.0);
        double x2 = fmin(fmax(gx + 0.5 * gw, 0.0), 1344.0);
        double y2 = fmin(fmax(gy + 0.5 * gh, 0.0), 800.0);
        SB[0] = x1; SB[1] = y1; SB[2] = x2; SB[3] = y2;
        float f = unflipf_dev(key);
        p.selScores[(size_t)t * NPRE + r] = 1.0 / (1.0 + exp(-(double)f));
      }
    }
  }
  gbar(p.bar, 6);

  // ---------------- P8: IoU mask (250 blocks, 10 compute waves) -------------
  if (bx < 250) {
    int t = bx / 25;
    int q = bx % 25;
    float* X1 = (float*)SMEM8;
    float* Y1 = X1 + 2048;
    float* X2 = X1 + 4096;
    float* Y2 = X1 + 6144;
    float* AR = X1 + 8192;
    const double* SB = p.selBoxes + (size_t)t * NPRE * 4;
    for (int i = tid; i < 2048; i += 1024) {
      float x1 = 0.f, y1 = 0.f, x2 = 0.f, y2 = 0.f;
      if (i < NPRE) {
        x1 = (float)SB[i * 4 + 0]; y1 = (float)SB[i * 4 + 1];
        x2 = (float)SB[i * 4 + 2]; y2 = (float)SB[i * 4 + 3];
      }
      X1[i] = x1; Y1[i] = y1; X2[i] = x2; Y2[i] = y2;
      AR[i] = (x2 - x1) * (y2 - y1);
    }
    __syncthreads();
    if (tid < 640) {
      int g = q + 25 * wave;  // [0,250)
      int i0 = g * 8;
      float x1i[8], y1i[8], x2i[8], y2i[8], ai[8];
#pragma unroll
      for (int r = 0; r < 8; r++) {
        int i = i0 + r;
        x1i[r] = X1[i]; y1i[r] = Y1[i]; x2i[r] = X2[i]; y2i[r] = Y2[i];
        ai[r] = AR[i];
      }
      int c0 = i0 >> 6;
      int j0 = c0 * 64 + lane;
      float cx1 = X1[j0], cy1 = Y1[j0], cx2 = X2[j0], cy2 = Y2[j0],
            car = AR[j0];
      for (int k = c0; k < 32; k++) {
        float nx1 = 0.f, ny1 = 0.f, nx2 = 0.f, ny2 = 0.f, nar = 0.f;
        if (k + 1 < 32) {
          int jn = (k + 1) * 64 + lane;
          nx1 = X1[jn]; ny1 = Y1[jn]; nx2 = X2[jn]; ny2 = Y2[jn];
          nar = AR[jn];
        }
        int j = k * 64 + lane;
        bool jin = j < NPRE;
        bool pred[8], need[8];
        bool needAny = false;
#pragma unroll
        for (int r = 0; r < 8; r++) {
          int i = i0 + r;
          bool valid = jin && (j > i);
          float lx = fmaxf(x1i[r], cx1), ly = fmaxf(y1i[r], cy1);
          float rx = fminf(x2i[r], cx2), ry = fminf(y2i[r], cy2);
          float w = fmaxf(rx - lx, 0.0f), h = fmaxf(ry - ly, 0.0f);
          float inter = w * h;
          float uni = fmaxf(ai[r] + car - inter, 1e-6f);
          float diff = inter - 0.7f * uni;
          pred[r] = valid && (diff > 0.0f);
          need[r] = valid && (fabsf(diff) <= 4.0f + 1e-5f * uni);
          needAny |= need[r];
        }
        if (__any(needAny)) {
#pragma unroll
          for (int r = 0; r < 8; r++) {
            if (need[r]) {
              int i = i0 + r;
              double a0 = SB[i * 4 + 0], b0 = SB[i * 4 + 1];
              double a2 = SB[i * 4 + 2], b2 = SB[i * 4 + 3];
              double c0d = SB[j * 4 + 0], d0 = SB[j * 4 + 1];
              double c2 = SB[j * 4 + 2], d2 = SB[j * 4 + 3];
              double dai = (a2 - a0) * (b2 - b0);
              double daj = (c2 - c0d) * (d2 - d0);
              double lxd = fmax(a0, c0d), lyd = fmax(b0, d0);
              double rxd = fmin(a2, c2), ryd = fmin(b2, d2);
              double wd = fmax(rxd - lxd, 0.0), hd = fmax(ryd - lyd, 0.0);
              double interd = wd * hd;
              double unid = fmax(dai + daj - interd, 1e-6);
              pred[r] = (interd / unid) > 0.7;
            }
          }
        }
#pragma unroll
        for (int r = 0; r < 8; r++) {
          unsigned long long word = __ballot(pred[r]);
          if (lane == 0) p.mask[((size_t)t * NPRE + i0 + r) * 32 + k] = word;
        }
        cx1 = nx1; cy1 = ny1; cx2 = nx2; cy2 = ny2; car = nar;
      }
    }
  }
  gbar(p.bar, 7);

  // ---------------- P9: greedy NMS + fused re-rank (10 blocks) --------------
  if (bx < 10) {
    int t = bx;
    unsigned long long* ring = SMEM8;  // RING*1024 = 6144 u64
    volatile int* rdy = g_ready;
    volatile int* cons = &g_cons;
    const unsigned long long* MK = p.mask + (size_t)t * NPRE * 32;
    for (int i = tid; i < GRP_N; i += 1024) g_ready[i] = 0;
    if (tid == 0) g_cons = 0;
    __syncthreads();

    if (wave >= 1 && wave <= 3) {
      // producers (3)
      for (int g = wave - 1; g < GRP_N; g += 3) {
        while (g - *cons >= RING) __builtin_amdgcn_s_sleep(1);
        unsigned long long v[16];
#pragma unroll
        for (int k = 0; k < 16; k++) {
          int idx = k * 64 + lane;
          int row = g * 32 + (idx >> 5);
          v[k] = (row < NPRE) ? MK[(size_t)row * 32 + (idx & 31)] : 0ull;
        }
        int slot = g % RING;
#pragma unroll
        for (int k = 0; k < 16; k++)
          ring[slot * 1024 + k * 64 + lane] = v[k];
        __threadfence_block();
        if (lane == 0) rdy[g] = 1;
      }
    } else if (wave == 0) {
      // consumer
      unsigned long long supp = 0ull, keep = 0ull;
      auto doGroup = [&](int g, int base) {
        while (rdy[g] == 0) { }
        __threadfence_block();
        int slot = g % RING;
        int c = g >> 1;
        unsigned long long rv[32];
#pragma unroll
        for (int r = 0; r < 32; r++)
          rv[r] = ring[slot * 1024 + r * 32 + (lane & 31)];
        unsigned int sh = (unsigned int)(supp >> base);
        unsigned int s32 =
            (unsigned int)__builtin_amdgcn_readlane((int)sh, c);
        unsigned int kg = 0;
#pragma unroll
        for (int r = 0; r < 32; r++) {
          unsigned int rvh = (unsigned int)(rv[r] >> base);
          bool kp = (s32 & (1u << r)) == 0u;
          kg |= kp ? (1u << r) : 0u;
          s32 |= kp ? rvh : 0u;
        }
        kg = (unsigned int)__builtin_amdgcn_readlane((int)kg, c);
#pragma unroll
        for (int r = 0; r < 32; r++) {
          if (kg & (1u << r)) supp |= rv[r];
        }
        keep |= (lane == c) ? ((unsigned long long)kg << base) : 0ull;
        __threadfence_block();
        if (lane == 63) *cons = g + 1;
      };
      for (int g = 0; g + 1 < GRP_N; g += 2) {
        doGroup(g, 0);
        doGroup(g + 1, 32);
      }
      doGroup(GRP_N - 1, 0);
      if (lane < 32) g_kw[lane] = keep;
    }
    __syncthreads();

    // fused re-rank (all 16 waves)
    for (int ch = wave; ch < 32; ch += 16) {
      int i = ch * 64 + lane;
      bool inr = i < NPRE;
      bool kb = inr && ((g_kw[ch] >> lane) & 1ull);
      bool A =
          kb && (inr ? (p.selScores[(size_t)t * NPRE + i] > -0.5) : false);
      bool B = inr && !A;
      unsigned long long wa = __ballot(A);
      unsigned long long wb = __ballot(B);
      if (lane == 0) { g_aw[ch] = wa; g_bw[ch] = wb; }
    }
    __syncthreads();
    if (tid == 0) {
      unsigned int ca = 0, cb = 0;
      for (int w = 0; w < 32; w++) {
        g_prefA[w] = ca; ca += __popcll(g_aw[w]);
        g_prefB[w] = cb; cb += __popcll(g_bw[w]);
      }
      g_prefA[32] = ca; g_prefB[32] = cb;
    }
    __syncthreads();
    unsigned int KA = g_prefA[32];
    for (int i = tid; i < NPRE; i += 1024) {
      int w = i >> 6, bpos = i & 63;
      unsigned long long below =
          (bpos == 0) ? 0ull : (~0ull >> (64 - bpos));
      bool kb = (g_kw[w] >> bpos) & 1ull;
      double s = p.selScores[(size_t)t * NPRE + i];
      bool A = kb && (s > -0.5);
      unsigned int slot;
      double outs;
      if (A) {
        slot = g_prefA[w] + (unsigned int)__popcll(g_aw[w] & below);
        outs = s;
      } else {
        slot = KA + g_prefB[w] + (unsigned int)__popcll(g_bw[w] & below);
        outs = -1.0;
      }
      if (slot < NPOST) {
        p.postScores[(size_t)t * NPOST + slot] = outs;
        const double* SB = p.selBoxes + ((size_t)t * NPRE + i) * 4;
        float* PB = p.postBoxes + ((size_t)t * NPOST + slot) * 4;
        PB[0] = (float)SB[0]; PB[1] = (float)SB[1];
        PB[2] = (float)SB[2]; PB[3] = (float)SB[3];
      }
    }
  }
  gbar(p.bar, 8);

  // ---------------- P10: final top-1000 rank (160 blocks) -------------------
  if (bx < 160) {
    int b = bx / 80;
    int rem = bx % 80;
    int s = rem >> 2;
    int ec = rem & 3;
    int j0 = s * 256;
    unsigned long long* kj = SMEM8;  // 256
    if (tid < 256) {
      int e = j0 + tid;
      unsigned long long v = 0ull;
      if (e < 5000) {
        int l = e / 1000, slot = e - l * 1000;
        int t = l * 2 + b;
        v = flip64_dev(p.postScores[(size_t)t * NPOST + slot]);
      }
      kj[tid] = v;
    }
    __syncthreads();
    if (tid < 256) {
      int eidx[5];
      unsigned long long ke[5];
      unsigned int r[5];
#pragma unroll
      for (int k = 0; k < 5; k++) {
        int e = ec * 1280 + k * 256 + tid;
        eidx[k] = (e < 5000) ? e : -1;
        if (eidx[k] >= 0) {
          int l = e / 1000, slot = e - l * 1000;
          int t = l * 2 + b;
          ke[k] = flip64_dev(p.postScores[(size_t)t * NPOST + slot]);
        } else {
          ke[k] = 0ull;
        }
        r[k] = 0;
      }
      for (int j = 0; j < 256; j++) {
        unsigned long long vj = kj[j];
        int jg = j0 + j;
#pragma unroll
        for (int k = 0; k < 5; k++)
          r[k] += (vj > ke[k] || (vj == ke[k] && jg < eidx[k])) ? 1u : 0u;
      }
#pragma unroll
      for (int k = 0; k < 5; k++)
        if (eidx[k] >= 0)
          p.partial[((size_t)b * 20 + s) * 5000 + eidx[k]] = r[k];
    }
  }
  gbar(p.bar, 9);

  // ---------------- P11: reduce ranks, gather output (10 blocks) ------------
  if (bx < 10 && tid < 1000) {
    int b = bx / 5;
    int ch = bx % 5;
    int e = ch * 1000 + tid;
    unsigned int r = 0;
#pragma unroll
    for (int s = 0; s < 20; s++)
      r += p.partial[((size_t)b * 20 + s) * 5000 + e];
    if (r < NPOST) {
      int l = e / 1000, slot = e - l * 1000;
      int t = l * 2 + b;
      const float* PB = p.postBoxes + ((size_t)t * NPOST + slot) * 4;
      float* O = p.out + ((size_t)b * NPOST + r) * 4;
      O[0] = PB[0]; O[1] = PB[1]; O[2] = PB[2]; O[3] = PB[3];
    }
  }
}

extern "C" void kernel_launch(void* const* d_in, const int* in_sizes, int n_in,
                              void* d_out, int out_size, void* d_ws,
                              size_t ws_size, hipStream_t stream) {
  RPNParams p;
  bool interleaved = (n_in >= 2) && (in_sizes[1] == 4 * in_sizes[0]);
  for (int l = 0; l < 5; l++) {
    if (interleaved) {
      p.cls[l]  = (const float*)d_in[3 * l + 0];
      p.bbox[l] = (const float*)d_in[3 * l + 1];
      p.anc[l]  = (const float*)d_in[3 * l + 2];
    } else {
      p.cls[l]  = (const float*)d_in[l];
      p.bbox[l] = (const float*)d_in[5 + l];
      p.anc[l]  = (const float*)d_in[10 + l];
    }
  }
  char* w = (char*)d_ws;
  size_t off = 0;
  auto alloc = [&](size_t bytes) {
    off = (off + 255) & ~(size_t)255;
    void* r = w + off;
    off += bytes;
    return r;
  };
  p.bar       = (unsigned int*)alloc(64 * 4);
  p.mainCount = (unsigned int*)alloc(10 * 4);
  p.candCount = (unsigned int*)alloc(10 * 4);
  size_t zbytes = off;  // zeroed region: barriers + atomic counters
  p.hist       = (unsigned int*)alloc((size_t)70 * 16384 * 4);
  p.histT      = (unsigned int*)alloc((size_t)8 * 16384 * 4);
  p.Bstar      = (unsigned int*)alloc(10 * 4);
  p.mainEK     = (unsigned long long*)alloc((size_t)10 * 2048 * 8);
  p.candEK     = (unsigned long long*)alloc((size_t)10 * 8192 * 8);
  p.ekG        = (unsigned long long*)alloc((size_t)10 * 2048 * 8);
  p.partialR   = (unsigned int*)alloc((size_t)10 * 8 * 2048 * 4);
  p.selBoxes   = (double*)alloc((size_t)10 * NPRE * 4 * 8);
  p.selScores  = (double*)alloc((size_t)10 * NPRE * 8);
  p.mask       = (unsigned long long*)alloc((size_t)10 * NPRE * 32 * 8);
  p.postScores = (double*)alloc((size_t)10 * NPOST * 8);
  p.postBoxes  = (float*)alloc((size_t)10 * NPOST * 4 * 4);
  p.partial    = (unsigned int*)alloc((size_t)2 * 20 * 5000 * 4);
  p.out = (float*)d_out;
  (void)ws_size; (void)out_size;

  hipMemsetAsync(d_ws, 0, zbytes, stream);
  k_mega<<<dim3(NBLK), dim3(1024), 0, stream>>>(p);
}

// Round 18
// 1078.048 us; speedup vs baseline: 1.2129x; 1.2129x over previous
//
#include <hip/hip_runtime.h>
#include <cmath>

// ---------------------------------------------------------------------------
// RPN head post-processing -- exact-semantics HIP port, MEGA-FUSED (R18).
//
// R17 PM: mega-fusion regressed 3x (1240us) because the barrier spin used
// ACQUIRE atomic loads at agent scope -- each poll iteration emits cache
// invalidates (buffer_inv), and ~246 idle blocks polling created a device-
// wide TCC invalidate storm that stalled every active block's memory.
// R18: canonical relaxed-spin barrier -- release fence + RELAXED add,
// RELAXED polling (no per-poll cache maintenance), ONE acquire fence after
// exit. Phase bodies unchanged from R17 (they are the proven R16 kernels).
// ---------------------------------------------------------------------------

#define NPRE 2000
#define NPOST 1000
#define NBLK 256

static __device__ __forceinline__ unsigned int flipf_dev(float f) {
  unsigned int u = __float_as_uint(f);
  return (u & 0x80000000u) ? ~u : (u | 0x80000000u);
}
static __device__ __forceinline__ float unflipf_dev(unsigned int k) {
  unsigned int u = (k & 0x80000000u) ? (k ^ 0x80000000u) : ~k;
  return __uint_as_float(u);
}
static __device__ __forceinline__ unsigned long long flip64_dev(double d) {
  unsigned long long u = (unsigned long long)__double_as_longlong(d);
  return (u & 0x8000000000000000ull) ? ~u : (u | 0x8000000000000000ull);
}

struct RPNParams {
  const float* cls[5];
  const float* bbox[5];
  const float* anc[5];
  unsigned int* bar;           // [64] barrier counters (zeroed)
  unsigned int* mainCount;     // [10] (zeroed)
  unsigned int* candCount;     // [10] (zeroed)
  unsigned int* hist;          // [70][16384]
  unsigned int* histT;         // [8][16384]
  unsigned int* Bstar;         // [10]
  unsigned long long* mainEK;  // [10][2048]
  unsigned long long* candEK;  // [10][8192]
  unsigned long long* ekG;     // [10][2048]
  unsigned int* partialR;      // [10][8][2048]
  double* selBoxes;            // [10][2000][4]
  double* selScores;           // [10][2000]
  unsigned long long* mask;    // [10][2000][32]
  double* postScores;          // [10][1000]
  float* postBoxes;            // [10][1000][4]
  unsigned int* partial;       // [2][20][5000]
  float* out;                  // [2][1000][4]
};

__device__ __constant__ int c_NL[5]  = {201600, 50400, 12600, 3150, 819};
__device__ __constant__ int c_HW[5]  = {67200, 16800, 4200, 1050, 273};
__device__ __constant__ int c_BPT[8] = {99, 99, 25, 25, 7, 7, 2, 2};
__device__ __constant__ int c_BPT12[8] = {25, 25, 7, 7, 2, 2, 1, 1};
__device__ __constant__ int c_HSTART[8] = {0, 25, 50, 57, 64, 66, 68, 69};

static __device__ __forceinline__ void map_block(int bx, int& t, int& chunk) {
  int start = 0;
  t = 0;
  for (int k = 0; k < 8; k++) {
    if (bx < start + c_BPT[k]) { t = k; break; }
    start += c_BPT[k];
  }
  chunk = bx - start;
}
static __device__ __forceinline__ void map_block12(int bx, int& t, int& chunk) {
  int start = 0;
  t = 0;
  for (int k = 0; k < 8; k++) {
    if (bx < start + c_BPT12[k]) { t = k; break; }
    start += c_BPT12[k];
  }
  chunk = bx - start;
}

// device-scope barrier: release fence + RELAXED add; RELAXED spin (no cache
// maintenance per poll!); one acquire fence after exit.
static __device__ __forceinline__ void gbar(unsigned int* bar, int ph) {
  __syncthreads();
  if (threadIdx.x == 0) {
    __threadfence();  // release prior global writes
    __hip_atomic_fetch_add(&bar[ph], 1u, __ATOMIC_RELAXED,
                           __HIP_MEMORY_SCOPE_AGENT);
    while (__hip_atomic_load(&bar[ph], __ATOMIC_RELAXED,
                             __HIP_MEMORY_SCOPE_AGENT) < (unsigned)NBLK)
      __builtin_amdgcn_s_sleep(8);
  }
  __syncthreads();
  __threadfence();  // acquire once per barrier (bounded, not per-poll)
}

#define GRP_N 63
#define RING 6

__global__ __launch_bounds__(1024) void k_mega(RPNParams p) {
  __shared__ unsigned long long SMEM8[8768];  // 70144 B union
  __shared__ int g_gsel;
  __shared__ unsigned int g_baseAbove;
  __shared__ int g_ready[GRP_N];
  __shared__ int g_cons;
  __shared__ unsigned long long g_kw[32], g_aw[32], g_bw[32];
  __shared__ unsigned int g_prefA[33], g_prefB[33];

  int bx = blockIdx.x;
  int tid = threadIdx.x;
  int wave = tid >> 6, lane = tid & 63;

  // ---------------- P1: private 14-bit histogram (70 blocks) ----------------
  if (bx < 70) {
    unsigned int* lh = (unsigned int*)SMEM8;  // 16384
    int t, chunk;
    map_block12(bx, t, chunk);
    int l = t >> 1, b = t & 1;
    int N = c_NL[l], HW = c_HW[l];
    const float* cls = p.cls[l] + (size_t)b * 3 * HW;
    for (int i = tid; i < 16384; i += 1024) lh[i] = 0;
    __syncthreads();
    int base = chunk * 8192 + tid;
#pragma unroll
    for (int k = 0; k < 8; k++) {
      int n = base + k * 1024;
      if (n < N) {
        int a = n % 3, hw = n / 3;
        unsigned int key = flipf_dev(cls[a * HW + hw]);
        atomicAdd(&lh[key >> 18], 1u);
      }
    }
    __syncthreads();
    unsigned int* hout = p.hist + (size_t)bx * 16384;
    for (int i = tid; i < 16384; i += 1024) hout[i] = lh[i];
  }
  gbar(p.bar, 0);

  // ---------------- P2: reduce private hists (128 blocks) -------------------
  if (bx < 128) {
    int t = bx >> 4;
    int slice = bx & 15;
    int bin = slice * 1024 + tid;
    int start = c_HSTART[t];
    int bpt = c_BPT12[t];
    unsigned int s0 = 0, s1 = 0, s2 = 0, s3 = 0;
    int bb = 0;
    for (; bb + 4 <= bpt; bb += 4) {
      s0 += p.hist[(size_t)(start + bb + 0) * 16384 + bin];
      s1 += p.hist[(size_t)(start + bb + 1) * 16384 + bin];
      s2 += p.hist[(size_t)(start + bb + 2) * 16384 + bin];
      s3 += p.hist[(size_t)(start + bb + 3) * 16384 + bin];
    }
    for (; bb < bpt; bb++) s0 += p.hist[(size_t)(start + bb) * 16384 + bin];
    p.histT[(size_t)t * 16384 + bin] = s0 + s1 + s2 + s3;
  }
  gbar(p.bar, 1);

  // ---------------- P3: find threshold bucket (8 blocks) --------------------
  if (bx < 8) {
    int t = bx;
    unsigned int* H = (unsigned int*)SMEM8;     // 16384
    unsigned int* S = H + 16384;                // 1024
    const unsigned int* hT = p.histT + (size_t)t * 16384;
    for (int bin = tid; bin < 16384; bin += 1024) H[bin] = hT[bin];
    __syncthreads();
    {
      unsigned int s = 0;
#pragma unroll
      for (int k = 0; k < 16; k++) s += H[tid * 16 + k];
      S[tid] = s;
    }
    __syncthreads();
    for (int off = 1; off < 1024; off <<= 1) {
      unsigned int add = (tid + off < 1024) ? S[tid + off] : 0u;
      __syncthreads();
      S[tid] += add;
      __syncthreads();
    }
    const unsigned int need = NPRE;
    if (S[tid] >= need && (tid == 1023 || S[tid + 1] < need)) {
      g_gsel = tid;
      g_baseAbove = (tid == 1023) ? 0u : S[tid + 1];
    }
    __syncthreads();
    if (tid == 0) {
      int gg = g_gsel;
      unsigned int c = g_baseAbove;
      int bstar = gg * 16;
      for (int bb = 15; bb >= 0; bb--) {
        c += H[gg * 16 + bb];
        if (c >= need) { bstar = gg * 16 + bb; break; }
      }
      p.Bstar[t] = (unsigned int)bstar;
    }
  }
  gbar(p.bar, 2);

  // ---------------- P4: compaction (266 units over 256 blocks) --------------
  for (int u = bx; u < 266; u += NBLK) {
    int t, chunk;
    map_block(u, t, chunk);
    int l = t >> 1, b = t & 1;
    int N = c_NL[l], HW = c_HW[l];
    const float* cls = p.cls[l] + (size_t)b * 3 * HW;
    unsigned int Bs = p.Bstar[t];
    int base = chunk * 2048 + tid;
    for (int k = 0; k < 2; k++) {
      int n = base + k * 1024;
      if (n < N) {
        int a = n % 3, hw = n / 3;
        unsigned int key = flipf_dev(cls[a * HW + hw]);
        unsigned int hi = key >> 18;
        unsigned long long ek =
            ((unsigned long long)key << 32) | (unsigned int)(~(unsigned int)n);
        if (hi > Bs) {
          unsigned int pos = atomicAdd(&p.mainCount[t], 1u);
          if (pos < 2048u) p.mainEK[(size_t)t * 2048 + pos] = ek;
        } else if (hi == Bs) {
          unsigned int pos = atomicAdd(&p.candCount[t], 1u);
          if (pos < 8192u) p.candEK[(size_t)t * 8192 + pos] = ek;
        }
      }
    }
  }
  gbar(p.bar, 3);

  // ---------------- P5: fill ekG (10 blocks, 256 threads, no sync) ----------
  if (bx < 10 && tid < 256) {
    int t = bx;
    int l = t >> 1, b = t & 1;
    int N = c_NL[l], HW = c_HW[l];
    unsigned long long* ekG = p.ekG + (size_t)t * 2048;
    if (N >= NPRE) {
      unsigned int cGT = min(p.mainCount[t], 2000u);
      unsigned int nC = min(p.candCount[t], 8192u);
      unsigned int needIn = 2000u - cGT;
      for (unsigned int m = tid; m < cGT; m += 256)
        ekG[m] = p.mainEK[(size_t)t * 2048 + m];
      const unsigned long long* cek = p.candEK + (size_t)t * 8192;
      for (unsigned int e = tid; e < nC; e += 256) {
        unsigned long long ve = cek[e];
        unsigned int r = 0;
        for (unsigned int j = 0; j < nC; j++) r += (cek[j] > ve) ? 1u : 0u;
        if (r < needIn) ekG[cGT + r] = ve;
      }
      for (unsigned int r2 = 2000u + tid; r2 < 2048u; r2 += 256)
        ekG[r2] = (unsigned long long)(unsigned int)(~r2);
    } else {
      const float* cls = p.cls[l] + (size_t)b * 3 * HW;
      for (int r = tid; r < 2048; r += 256) {
        if (r < N) {
          int a = r % 3, hw = r / 3;
          unsigned int key = flipf_dev(cls[a * HW + hw]);
          ekG[r] = ((unsigned long long)key << 32) |
                   (unsigned int)(~(unsigned int)r);
        } else {
          ekG[r] = (unsigned long long)(unsigned int)(~(unsigned int)r);
        }
      }
    }
  }
  gbar(p.bar, 4);

  // ---------------- P6: sliced counting-rank (80 blocks) --------------------
  if (bx < 80) {
    int t = bx >> 3;
    int s = bx & 7;
    unsigned long long* sl = SMEM8;  // 256
    const unsigned long long* ekG = p.ekG + (size_t)t * 2048;
    if (tid < 256) sl[tid] = ekG[s * 256 + tid];
    __syncthreads();
    if (tid < 256) {
      unsigned long long ve[8];
      unsigned int r[8];
#pragma unroll
      for (int k = 0; k < 8; k++) {
        ve[k] = ekG[k * 256 + tid];
        r[k] = 0;
      }
      for (int j = 0; j < 256; j++) {
        unsigned long long vj = sl[j];
#pragma unroll
        for (int k = 0; k < 8; k++) r[k] += (vj > ve[k]) ? 1u : 0u;
      }
      unsigned int* out = p.partialR + ((size_t)t * 8 + s) * 2048;
#pragma unroll
      for (int k = 0; k < 8; k++) out[k * 256 + tid] = r[k];
    }
  }
  gbar(p.bar, 5);

  // ---------------- P7: scatter + fp64 decode (10 blocks) -------------------
  if (bx < 10) {
    int t = bx;
    int l = t >> 1, b = t & 1;
    int HW = c_HW[l];
    unsigned long long* srt = SMEM8;  // 2048
    const unsigned long long* ekG = p.ekG + (size_t)t * 2048;
    for (int e = tid; e < 2048; e += 1024) {
      unsigned int rk = 0;
#pragma unroll
      for (int s = 0; s < 8; s++)
        rk += p.partialR[((size_t)t * 8 + s) * 2048 + e];
      srt[rk] = ekG[e];
    }
    __syncthreads();
    const double RCLIP = fabs(log(16.0 / 1000.0));
    const float* bbx = p.bbox[l] + (size_t)b * 12 * HW;
    const float* anc = p.anc[l];
    for (int r = tid; r < NPRE; r += 1024) {
      unsigned long long v = srt[r];
      unsigned int key = (unsigned int)(v >> 32);
      double* SB = p.selBoxes + ((size_t)t * NPRE + r) * 4;
      if (key == 0u) {
        SB[0] = 0.0; SB[1] = 0.0; SB[2] = 0.0; SB[3] = 0.0;
        p.selScores[(size_t)t * NPRE + r] = -1.0;
      } else {
        unsigned int idx = ~(unsigned int)(v & 0xFFFFFFFFull);
        int a = (int)(idx % 3u);
        int hw = (int)(idx / 3u);
        double d0 = (double)bbx[(a * 4 + 0) * HW + hw];
        double d1 = (double)bbx[(a * 4 + 1) * HW + hw];
        double d2 = (double)bbx[(a * 4 + 2) * HW + hw];
        double d3 = (double)bbx[(a * 4 + 3) * HW + hw];
        double a0 = (double)anc[(size_t)idx * 4 + 0];
        double a1 = (double)anc[(size_t)idx * 4 + 1];
        double a2 = (double)anc[(size_t)idx * 4 + 2];
        double a3 = (double)anc[(size_t)idx * 4 + 3];
        double dw = fmin(fmax(d2, -RCLIP), RCLIP);
        double dh = fmin(fmax(d3, -RCLIP), RCLIP);
        double pw = a2 - a0, ph = a3 - a1;
        double px = (a0 + a2) * 0.5, py = (a1 + a3) * 0.5;
        double gw = pw * exp(dw), gh = ph * exp(dh);
        double gx = px + pw * d0, gy = py + ph * d1;
        double x1 = fmin(fmax(gx - 0.5 * gw, 0.0), 1344.0);
        double y1 = fmin(fmax(gy - 0.5 * gh, 0.0), 800.0);
        double x2 = fmin(fmax(gx + 0.5 * gw, 0.0), 1344.0);
        double y2 = fmin(fmax(gy + 0.5 * gh, 0.0), 800.0);
        SB[0] = x1; SB[1] = y1; SB[2] = x2; SB[3] = y2;
        float f = unflipf_dev(key);
        p.selScores[(size_t)t * NPRE + r] = 1.0 / (1.0 + exp(-(double)f));
      }
    }
  }
  gbar(p.bar, 6);

  // ---------------- P8: IoU mask (250 blocks, 10 compute waves) -------------
  if (bx < 250) {
    int t = bx / 25;
    int q = bx % 25;
    float* X1 = (float*)SMEM8;
    float* Y1 = X1 + 2048;
    float* X2 = X1 + 4096;
    float* Y2 = X1 + 6144;
    float* AR = X1 + 8192;
    const double* SB = p.selBoxes + (size_t)t * NPRE * 4;
    for (int i = tid; i < 2048; i += 1024) {
      float x1 = 0.f, y1 = 0.f, x2 = 0.f, y2 = 0.f;
      if (i < NPRE) {
        x1 = (float)SB[i * 4 + 0]; y1 = (float)SB[i * 4 + 1];
        x2 = (float)SB[i * 4 + 2]; y2 = (float)SB[i * 4 + 3];
      }
      X1[i] = x1; Y1[i] = y1; X2[i] = x2; Y2[i] = y2;
      AR[i] = (x2 - x1) * (y2 - y1);
    }
    __syncthreads();
    if (tid < 640) {
      int g = q + 25 * wave;  // [0,250)
      int i0 = g * 8;
      float x1i[8], y1i[8], x2i[8], y2i[8], ai[8];
#pragma unroll
      for (int r = 0; r < 8; r++) {
        int i = i0 + r;
        x1i[r] = X1[i]; y1i[r] = Y1[i]; x2i[r] = X2[i]; y2i[r] = Y2[i];
        ai[r] = AR[i];
      }
      int c0 = i0 >> 6;
      int j0 = c0 * 64 + lane;
      float cx1 = X1[j0], cy1 = Y1[j0], cx2 = X2[j0], cy2 = Y2[j0],
            car = AR[j0];
      for (int k = c0; k < 32; k++) {
        float nx1 = 0.f, ny1 = 0.f, nx2 = 0.f, ny2 = 0.f, nar = 0.f;
        if (k + 1 < 32) {
          int jn = (k + 1) * 64 + lane;
          nx1 = X1[jn]; ny1 = Y1[jn]; nx2 = X2[jn]; ny2 = Y2[jn];
          nar = AR[jn];
        }
        int j = k * 64 + lane;
        bool jin = j < NPRE;
        bool pred[8], need[8];
        bool needAny = false;
#pragma unroll
        for (int r = 0; r < 8; r++) {
          int i = i0 + r;
          bool valid = jin && (j > i);
          float lx = fmaxf(x1i[r], cx1), ly = fmaxf(y1i[r], cy1);
          float rx = fminf(x2i[r], cx2), ry = fminf(y2i[r], cy2);
          float w = fmaxf(rx - lx, 0.0f), h = fmaxf(ry - ly, 0.0f);
          float inter = w * h;
          float uni = fmaxf(ai[r] + car - inter, 1e-6f);
          float diff = inter - 0.7f * uni;
          pred[r] = valid && (diff > 0.0f);
          need[r] = valid && (fabsf(diff) <= 4.0f + 1e-5f * uni);
          needAny |= need[r];
        }
        if (__any(needAny)) {
#pragma unroll
          for (int r = 0; r < 8; r++) {
            if (need[r]) {
              int i = i0 + r;
              double a0 = SB[i * 4 + 0], b0 = SB[i * 4 + 1];
              double a2 = SB[i * 4 + 2], b2 = SB[i * 4 + 3];
              double c0d = SB[j * 4 + 0], d0 = SB[j * 4 + 1];
              double c2 = SB[j * 4 + 2], d2 = SB[j * 4 + 3];
              double dai = (a2 - a0) * (b2 - b0);
              double daj = (c2 - c0d) * (d2 - d0);
              double lxd = fmax(a0, c0d), lyd = fmax(b0, d0);
              double rxd = fmin(a2, c2), ryd = fmin(b2, d2);
              double wd = fmax(rxd - lxd, 0.0), hd = fmax(ryd - lyd, 0.0);
              double interd = wd * hd;
              double unid = fmax(dai + daj - interd, 1e-6);
              pred[r] = (interd / unid) > 0.7;
            }
          }
        }
#pragma unroll
        for (int r = 0; r < 8; r++) {
          unsigned long long word = __ballot(pred[r]);
          if (lane == 0) p.mask[((size_t)t * NPRE + i0 + r) * 32 + k] = word;
        }
        cx1 = nx1; cy1 = ny1; cx2 = nx2; cy2 = ny2; car = nar;
      }
    }
  }
  gbar(p.bar, 7);

  // ---------------- P9: greedy NMS + fused re-rank (10 blocks) --------------
  if (bx < 10) {
    int t = bx;
    unsigned long long* ring = SMEM8;  // RING*1024 = 6144 u64
    volatile int* rdy = g_ready;
    volatile int* cons = &g_cons;
    const unsigned long long* MK = p.mask + (size_t)t * NPRE * 32;
    for (int i = tid; i < GRP_N; i += 1024) g_ready[i] = 0;
    if (tid == 0) g_cons = 0;
    __syncthreads();

    if (wave >= 1 && wave <= 3) {
      // producers (3)
      for (int g = wave - 1; g < GRP_N; g += 3) {
        while (g - *cons >= RING) __builtin_amdgcn_s_sleep(1);
        unsigned long long v[16];
#pragma unroll
        for (int k = 0; k < 16; k++) {
          int idx = k * 64 + lane;
          int row = g * 32 + (idx >> 5);
          v[k] = (row < NPRE) ? MK[(size_t)row * 32 + (idx & 31)] : 0ull;
        }
        int slot = g % RING;
#pragma unroll
        for (int k = 0; k < 16; k++)
          ring[slot * 1024 + k * 64 + lane] = v[k];
        __threadfence_block();
        if (lane == 0) rdy[g] = 1;
      }
    } else if (wave == 0) {
      // consumer
      unsigned long long supp = 0ull, keep = 0ull;
      auto doGroup = [&](int g, int base) {
        while (rdy[g] == 0) { }
        __threadfence_block();
        int slot = g % RING;
        int c = g >> 1;
        unsigned long long rv[32];
#pragma unroll
        for (int r = 0; r < 32; r++)
          rv[r] = ring[slot * 1024 + r * 32 + (lane & 31)];
        unsigned int sh = (unsigned int)(supp >> base);
        unsigned int s32 =
            (unsigned int)__builtin_amdgcn_readlane((int)sh, c);
        unsigned int kg = 0;
#pragma unroll
        for (int r = 0; r < 32; r++) {
          unsigned int rvh = (unsigned int)(rv[r] >> base);
          bool kp = (s32 & (1u << r)) == 0u;
          kg |= kp ? (1u << r) : 0u;
          s32 |= kp ? rvh : 0u;
        }
        kg = (unsigned int)__builtin_amdgcn_readlane((int)kg, c);
#pragma unroll
        for (int r = 0; r < 32; r++) {
          if (kg & (1u << r)) supp |= rv[r];
        }
        keep |= (lane == c) ? ((unsigned long long)kg << base) : 0ull;
        __threadfence_block();
        if (lane == 63) *cons = g + 1;
      };
      for (int g = 0; g + 1 < GRP_N; g += 2) {
        doGroup(g, 0);
        doGroup(g + 1, 32);
      }
      doGroup(GRP_N - 1, 0);
      if (lane < 32) g_kw[lane] = keep;
    }
    __syncthreads();

    // fused re-rank (all 16 waves)
    for (int ch = wave; ch < 32; ch += 16) {
      int i = ch * 64 + lane;
      bool inr = i < NPRE;
      bool kb = inr && ((g_kw[ch] >> lane) & 1ull);
      bool A =
          kb && (inr ? (p.selScores[(size_t)t * NPRE + i] > -0.5) : false);
      bool B = inr && !A;
      unsigned long long wa = __ballot(A);
      unsigned long long wb = __ballot(B);
      if (lane == 0) { g_aw[ch] = wa; g_bw[ch] = wb; }
    }
    __syncthreads();
    if (tid == 0) {
      unsigned int ca = 0, cb = 0;
      for (int w = 0; w < 32; w++) {
        g_prefA[w] = ca; ca += __popcll(g_aw[w]);
        g_prefB[w] = cb; cb += __popcll(g_bw[w]);
      }
      g_prefA[32] = ca; g_prefB[32] = cb;
    }
    __syncthreads();
    unsigned int KA = g_prefA[32];
    for (int i = tid; i < NPRE; i += 1024) {
      int w = i >> 6, bpos = i & 63;
      unsigned long long below =
          (bpos == 0) ? 0ull : (~0ull >> (64 - bpos));
      bool kb = (g_kw[w] >> bpos) & 1ull;
      double s = p.selScores[(size_t)t * NPRE + i];
      bool A = kb && (s > -0.5);
      unsigned int slot;
      double outs;
      if (A) {
        slot = g_prefA[w] + (unsigned int)__popcll(g_aw[w] & below);
        outs = s;
      } else {
        slot = KA + g_prefB[w] + (unsigned int)__popcll(g_bw[w] & below);
        outs = -1.0;
      }
      if (slot < NPOST) {
        p.postScores[(size_t)t * NPOST + slot] = outs;
        const double* SB = p.selBoxes + ((size_t)t * NPRE + i) * 4;
        float* PB = p.postBoxes + ((size_t)t * NPOST + slot) * 4;
        PB[0] = (float)SB[0]; PB[1] = (float)SB[1];
        PB[2] = (float)SB[2]; PB[3] = (float)SB[3];
      }
    }
  }
  gbar(p.bar, 8);

  // ---------------- P10: final top-1000 rank (160 blocks) -------------------
  if (bx < 160) {
    int b = bx / 80;
    int rem = bx % 80;
    int s = rem >> 2;
    int ec = rem & 3;
    int j0 = s * 256;
    unsigned long long* kj = SMEM8;  // 256
    if (tid < 256) {
      int e = j0 + tid;
      unsigned long long v = 0ull;
      if (e < 5000) {
        int l = e / 1000, slot = e - l * 1000;
        int t = l * 2 + b;
        v = flip64_dev(p.postScores[(size_t)t * NPOST + slot]);
      }
      kj[tid] = v;
    }
    __syncthreads();
    if (tid < 256) {
      int eidx[5];
      unsigned long long ke[5];
      unsigned int r[5];
#pragma unroll
      for (int k = 0; k < 5; k++) {
        int e = ec * 1280 + k * 256 + tid;
        eidx[k] = (e < 5000) ? e : -1;
        if (eidx[k] >= 0) {
          int l = e / 1000, slot = e - l * 1000;
          int t = l * 2 + b;
          ke[k] = flip64_dev(p.postScores[(size_t)t * NPOST + slot]);
        } else {
          ke[k] = 0ull;
        }
        r[k] = 0;
      }
      for (int j = 0; j < 256; j++) {
        unsigned long long vj = kj[j];
        int jg = j0 + j;
#pragma unroll
        for (int k = 0; k < 5; k++)
          r[k] += (vj > ke[k] || (vj == ke[k] && jg < eidx[k])) ? 1u : 0u;
      }
#pragma unroll
      for (int k = 0; k < 5; k++)
        if (eidx[k] >= 0)
          p.partial[((size_t)b * 20 + s) * 5000 + eidx[k]] = r[k];
    }
  }
  gbar(p.bar, 9);

  // ---------------- P11: reduce ranks, gather output (10 blocks) ------------
  if (bx < 10 && tid < 1000) {
    int b = bx / 5;
    int ch = bx % 5;
    int e = ch * 1000 + tid;
    unsigned int r = 0;
#pragma unroll
    for (int s = 0; s < 20; s++)
      r += p.partial[((size_t)b * 20 + s) * 5000 + e];
    if (r < NPOST) {
      int l = e / 1000, slot = e - l * 1000;
      int t = l * 2 + b;
      const float* PB = p.postBoxes + ((size_t)t * NPOST + slot) * 4;
      float* O = p.out + ((size_t)b * NPOST + r) * 4;
      O[0] = PB[0]; O[1] = PB[1]; O[2] = PB[2]; O[3] = PB[3];
    }
  }
}

extern "C" void kernel_launch(void* const* d_in, const int* in_sizes, int n_in,
                              void* d_out, int out_size, void* d_ws,
                              size_t ws_size, hipStream_t stream) {
  RPNParams p;
  bool interleaved = (n_in >= 2) && (in_sizes[1] == 4 * in_sizes[0]);
  for (int l = 0; l < 5; l++) {
    if (interleaved) {
      p.cls[l]  = (const float*)d_in[3 * l + 0];
      p.bbox[l] = (const float*)d_in[3 * l + 1];
      p.anc[l]  = (const float*)d_in[3 * l + 2];
    } else {
      p.cls[l]  = (const float*)d_in[l];
      p.bbox[l] = (const float*)d_in[5 + l];
      p.anc[l]  = (const float*)d_in[10 + l];
    }
  }
  char* w = (char*)d_ws;
  size_t off = 0;
  auto alloc = [&](size_t bytes) {
    off = (off + 255) & ~(size_t)255;
    void* r = w + off;
    off += bytes;
    return r;
  };
  p.bar       = (unsigned int*)alloc(64 * 4);
  p.mainCount = (unsigned int*)alloc(10 * 4);
  p.candCount = (unsigned int*)alloc(10 * 4);
  size_t zbytes = off;  // zeroed region: barriers + atomic counters
  p.hist       = (unsigned int*)alloc((size_t)70 * 16384 * 4);
  p.histT      = (unsigned int*)alloc((size_t)8 * 16384 * 4);
  p.Bstar      = (unsigned int*)alloc(10 * 4);
  p.mainEK     = (unsigned long long*)alloc((size_t)10 * 2048 * 8);
  p.candEK     = (unsigned long long*)alloc((size_t)10 * 8192 * 8);
  p.ekG        = (unsigned long long*)alloc((size_t)10 * 2048 * 8);
  p.partialR   = (unsigned int*)alloc((size_t)10 * 8 * 2048 * 4);
  p.selBoxes   = (double*)alloc((size_t)10 * NPRE * 4 * 8);
  p.selScores  = (double*)alloc((size_t)10 * NPRE * 8);
  p.mask       = (unsigned long long*)alloc((size_t)10 * NPRE * 32 * 8);
  p.postScores = (double*)alloc((size_t)10 * NPOST * 8);
  p.postBoxes  = (float*)alloc((size_t)10 * NPOST * 4 * 4);
  p.partial    = (unsigned int*)alloc((size_t)2 * 20 * 5000 * 4);
  p.out = (float*)d_out;
  (void)ws_size; (void)out_size;

  hipMemsetAsync(d_ws, 0, zbytes, stream);
  k_mega<<<dim3(NBLK), dim3(1024), 0, stream>>>(p);
}

// Round 19
// 1024.708 us; speedup vs baseline: 1.2761x; 1.0521x over previous
//
#include <hip/hip_runtime.h>
#include <cmath>

// ---------------------------------------------------------------------------
// RPN head post-processing -- exact-semantics HIP port, MEGA-FUSED (R19).
//
// R17: acquire-poll barrier -> per-poll cache-invalidate storm (1240us).
// R18: relaxed polls -> 1017us; still throttled: ~250 idle blocks polling
// ONE line every 512cy = ~1200 same-line MALL transactions/us -> coherence-
// point queue backs up, backpressures the fabric, throttles ALL memory
// (26MB at 25GB/s effective). R19: two-level barrier -- 8 group lines (32
// arrivals each) + root + 8 per-group go-flag lines, polls at s_sleep(32);
// hot-line pressure down >250x. Phase bodies unchanged (proven R16 kernels).
// ---------------------------------------------------------------------------

#define NPRE 2000
#define NPOST 1000
#define NBLK 256

static __device__ __forceinline__ unsigned int flipf_dev(float f) {
  unsigned int u = __float_as_uint(f);
  return (u & 0x80000000u) ? ~u : (u | 0x80000000u);
}
static __device__ __forceinline__ float unflipf_dev(unsigned int k) {
  unsigned int u = (k & 0x80000000u) ? (k ^ 0x80000000u) : ~k;
  return __uint_as_float(u);
}
static __device__ __forceinline__ unsigned long long flip64_dev(double d) {
  unsigned long long u = (unsigned long long)__double_as_longlong(d);
  return (u & 0x8000000000000000ull) ? ~u : (u | 0x8000000000000000ull);
}

struct RPNParams {
  const float* cls[5];
  const float* bbox[5];
  const float* anc[5];
  unsigned int* bar;           // [10][544] two-level barrier lines (zeroed)
  unsigned int* mainCount;     // [10] (zeroed)
  unsigned int* candCount;     // [10] (zeroed)
  unsigned int* hist;          // [70][16384]
  unsigned int* histT;         // [8][16384]
  unsigned int* Bstar;         // [10]
  unsigned long long* mainEK;  // [10][2048]
  unsigned long long* candEK;  // [10][8192]
  unsigned long long* ekG;     // [10][2048]
  unsigned int* partialR;      // [10][8][2048]
  double* selBoxes;            // [10][2000][4]
  double* selScores;           // [10][2000]
  unsigned long long* mask;    // [10][2000][32]
  double* postScores;          // [10][1000]
  float* postBoxes;            // [10][1000][4]
  unsigned int* partial;       // [2][20][5000]
  float* out;                  // [2][1000][4]
};

__device__ __constant__ int c_NL[5]  = {201600, 50400, 12600, 3150, 819};
__device__ __constant__ int c_HW[5]  = {67200, 16800, 4200, 1050, 273};
__device__ __constant__ int c_BPT[8] = {99, 99, 25, 25, 7, 7, 2, 2};
__device__ __constant__ int c_BPT12[8] = {25, 25, 7, 7, 2, 2, 1, 1};
__device__ __constant__ int c_HSTART[8] = {0, 25, 50, 57, 64, 66, 68, 69};

static __device__ __forceinline__ void map_block(int bx, int& t, int& chunk) {
  int start = 0;
  t = 0;
  for (int k = 0; k < 8; k++) {
    if (bx < start + c_BPT[k]) { t = k; break; }
    start += c_BPT[k];
  }
  chunk = bx - start;
}
static __device__ __forceinline__ void map_block12(int bx, int& t, int& chunk) {
  int start = 0;
  t = 0;
  for (int k = 0; k < 8; k++) {
    if (bx < start + c_BPT12[k]) { t = k; break; }
    start += c_BPT12[k];
  }
  chunk = bx - start;
}

// Two-level device barrier. Layout per phase (544 u32 = 17 lines of 128B):
//   line g   (g<8)  : group-arrival counter (32 blocks each)
//   line 8          : root counter (8 group-leaders)
//   line 9+g (g<8)  : per-group go flag (polled by 32 blocks)
// Release fence before arrival; relaxed adds/stores/polls (no per-poll cache
// maintenance); one acquire fence after exit. Polls at s_sleep(32) ~0.85us.
static __device__ __forceinline__ void gbar(unsigned int* bar, int ph) {
  __syncthreads();
  if (threadIdx.x == 0) {
    unsigned int* base = bar + (size_t)ph * 544;
    int g = (int)(blockIdx.x >> 5);  // 8 groups of 32
    __threadfence();                 // release prior global writes
    unsigned int a = __hip_atomic_fetch_add(&base[g * 32], 1u,
                                            __ATOMIC_RELAXED,
                                            __HIP_MEMORY_SCOPE_AGENT);
    if (a == 31u) {  // last arrival in this group
      unsigned int r = __hip_atomic_fetch_add(&base[8 * 32], 1u,
                                              __ATOMIC_RELAXED,
                                              __HIP_MEMORY_SCOPE_AGENT);
      if (r == 7u) {  // last group: open all gates
        for (int i = 0; i < 8; i++)
          __hip_atomic_store(&base[(9 + i) * 32], 1u, __ATOMIC_RELAXED,
                             __HIP_MEMORY_SCOPE_AGENT);
      }
    }
    while (__hip_atomic_load(&base[(9 + g) * 32], __ATOMIC_RELAXED,
                             __HIP_MEMORY_SCOPE_AGENT) == 0u)
      __builtin_amdgcn_s_sleep(32);
  }
  __syncthreads();
  __threadfence();  // acquire once per barrier
}

#define GRP_N 63
#define RING 6

__global__ __launch_bounds__(1024) void k_mega(RPNParams p) {
  __shared__ unsigned long long SMEM8[8768];  // 70144 B union
  __shared__ int g_gsel;
  __shared__ unsigned int g_baseAbove;
  __shared__ int g_ready[GRP_N];
  __shared__ int g_cons;
  __shared__ unsigned long long g_kw[32], g_aw[32], g_bw[32];
  __shared__ unsigned int g_prefA[33], g_prefB[33];

  int bx = blockIdx.x;
  int tid = threadIdx.x;
  int wave = tid >> 6, lane = tid & 63;

  // ---------------- P1: private 14-bit histogram (70 blocks) ----------------
  if (bx < 70) {
    unsigned int* lh = (unsigned int*)SMEM8;  // 16384
    int t, chunk;
    map_block12(bx, t, chunk);
    int l = t >> 1, b = t & 1;
    int N = c_NL[l], HW = c_HW[l];
    const float* cls = p.cls[l] + (size_t)b * 3 * HW;
    for (int i = tid; i < 16384; i += 1024) lh[i] = 0;
    __syncthreads();
    int base = chunk * 8192 + tid;
#pragma unroll
    for (int k = 0; k < 8; k++) {
      int n = base + k * 1024;
      if (n < N) {
        int a = n % 3, hw = n / 3;
        unsigned int key = flipf_dev(cls[a * HW + hw]);
        atomicAdd(&lh[key >> 18], 1u);
      }
    }
    __syncthreads();
    unsigned int* hout = p.hist + (size_t)bx * 16384;
    for (int i = tid; i < 16384; i += 1024) hout[i] = lh[i];
  }
  gbar(p.bar, 0);

  // ---------------- P2: reduce private hists (128 blocks) -------------------
  if (bx < 128) {
    int t = bx >> 4;
    int slice = bx & 15;
    int bin = slice * 1024 + tid;
    int start = c_HSTART[t];
    int bpt = c_BPT12[t];
    unsigned int s0 = 0, s1 = 0, s2 = 0, s3 = 0;
    int bb = 0;
    for (; bb + 4 <= bpt; bb += 4) {
      s0 += p.hist[(size_t)(start + bb + 0) * 16384 + bin];
      s1 += p.hist[(size_t)(start + bb + 1) * 16384 + bin];
      s2 += p.hist[(size_t)(start + bb + 2) * 16384 + bin];
      s3 += p.hist[(size_t)(start + bb + 3) * 16384 + bin];
    }
    for (; bb < bpt; bb++) s0 += p.hist[(size_t)(start + bb) * 16384 + bin];
    p.histT[(size_t)t * 16384 + bin] = s0 + s1 + s2 + s3;
  }
  gbar(p.bar, 1);

  // ---------------- P3: find threshold bucket (8 blocks) --------------------
  if (bx < 8) {
    int t = bx;
    unsigned int* H = (unsigned int*)SMEM8;     // 16384
    unsigned int* S = H + 16384;                // 1024
    const unsigned int* hT = p.histT + (size_t)t * 16384;
    for (int bin = tid; bin < 16384; bin += 1024) H[bin] = hT[bin];
    __syncthreads();
    {
      unsigned int s = 0;
#pragma unroll
      for (int k = 0; k < 16; k++) s += H[tid * 16 + k];
      S[tid] = s;
    }
    __syncthreads();
    for (int off = 1; off < 1024; off <<= 1) {
      unsigned int add = (tid + off < 1024) ? S[tid + off] : 0u;
      __syncthreads();
      S[tid] += add;
      __syncthreads();
    }
    const unsigned int need = NPRE;
    if (S[tid] >= need && (tid == 1023 || S[tid + 1] < need)) {
      g_gsel = tid;
      g_baseAbove = (tid == 1023) ? 0u : S[tid + 1];
    }
    __syncthreads();
    if (tid == 0) {
      int gg = g_gsel;
      unsigned int c = g_baseAbove;
      int bstar = gg * 16;
      for (int bb = 15; bb >= 0; bb--) {
        c += H[gg * 16 + bb];
        if (c >= need) { bstar = gg * 16 + bb; break; }
      }
      p.Bstar[t] = (unsigned int)bstar;
    }
  }
  gbar(p.bar, 2);

  // ---------------- P4: compaction (266 units over 256 blocks) --------------
  for (int u = bx; u < 266; u += NBLK) {
    int t, chunk;
    map_block(u, t, chunk);
    int l = t >> 1, b = t & 1;
    int N = c_NL[l], HW = c_HW[l];
    const float* cls = p.cls[l] + (size_t)b * 3 * HW;
    unsigned int Bs = p.Bstar[t];
    int base = chunk * 2048 + tid;
    for (int k = 0; k < 2; k++) {
      int n = base + k * 1024;
      if (n < N) {
        int a = n % 3, hw = n / 3;
        unsigned int key = flipf_dev(cls[a * HW + hw]);
        unsigned int hi = key >> 18;
        unsigned long long ek =
            ((unsigned long long)key << 32) | (unsigned int)(~(unsigned int)n);
        if (hi > Bs) {
          unsigned int pos = atomicAdd(&p.mainCount[t], 1u);
          if (pos < 2048u) p.mainEK[(size_t)t * 2048 + pos] = ek;
        } else if (hi == Bs) {
          unsigned int pos = atomicAdd(&p.candCount[t], 1u);
          if (pos < 8192u) p.candEK[(size_t)t * 8192 + pos] = ek;
        }
      }
    }
  }
  gbar(p.bar, 3);

  // ---------------- P5: fill ekG (10 blocks, 256 threads, no sync) ----------
  if (bx < 10 && tid < 256) {
    int t = bx;
    int l = t >> 1, b = t & 1;
    int N = c_NL[l], HW = c_HW[l];
    unsigned long long* ekG = p.ekG + (size_t)t * 2048;
    if (N >= NPRE) {
      unsigned int cGT = min(p.mainCount[t], 2000u);
      unsigned int nC = min(p.candCount[t], 8192u);
      unsigned int needIn = 2000u - cGT;
      for (unsigned int m = tid; m < cGT; m += 256)
        ekG[m] = p.mainEK[(size_t)t * 2048 + m];
      const unsigned long long* cek = p.candEK + (size_t)t * 8192;
      for (unsigned int e = tid; e < nC; e += 256) {
        unsigned long long ve = cek[e];
        unsigned int r = 0;
        for (unsigned int j = 0; j < nC; j++) r += (cek[j] > ve) ? 1u : 0u;
        if (r < needIn) ekG[cGT + r] = ve;
      }
      for (unsigned int r2 = 2000u + tid; r2 < 2048u; r2 += 256)
        ekG[r2] = (unsigned long long)(unsigned int)(~r2);
    } else {
      const float* cls = p.cls[l] + (size_t)b * 3 * HW;
      for (int r = tid; r < 2048; r += 256) {
        if (r < N) {
          int a = r % 3, hw = r / 3;
          unsigned int key = flipf_dev(cls[a * HW + hw]);
          ekG[r] = ((unsigned long long)key << 32) |
                   (unsigned int)(~(unsigned int)r);
        } else {
          ekG[r] = (unsigned long long)(unsigned int)(~(unsigned int)r);
        }
      }
    }
  }
  gbar(p.bar, 4);

  // ---------------- P6: sliced counting-rank (80 blocks) --------------------
  if (bx < 80) {
    int t = bx >> 3;
    int s = bx & 7;
    unsigned long long* sl = SMEM8;  // 256
    const unsigned long long* ekG = p.ekG + (size_t)t * 2048;
    if (tid < 256) sl[tid] = ekG[s * 256 + tid];
    __syncthreads();
    if (tid < 256) {
      unsigned long long ve[8];
      unsigned int r[8];
#pragma unroll
      for (int k = 0; k < 8; k++) {
        ve[k] = ekG[k * 256 + tid];
        r[k] = 0;
      }
      for (int j = 0; j < 256; j++) {
        unsigned long long vj = sl[j];
#pragma unroll
        for (int k = 0; k < 8; k++) r[k] += (vj > ve[k]) ? 1u : 0u;
      }
      unsigned int* out = p.partialR + ((size_t)t * 8 + s) * 2048;
#pragma unroll
      for (int k = 0; k < 8; k++) out[k * 256 + tid] = r[k];
    }
  }
  gbar(p.bar, 5);

  // ---------------- P7: scatter + fp64 decode (10 blocks) -------------------
  if (bx < 10) {
    int t = bx;
    int l = t >> 1, b = t & 1;
    int HW = c_HW[l];
    unsigned long long* srt = SMEM8;  // 2048
    const unsigned long long* ekG = p.ekG + (size_t)t * 2048;
    for (int e = tid; e < 2048; e += 1024) {
      unsigned int rk = 0;
#pragma unroll
      for (int s = 0; s < 8; s++)
        rk += p.partialR[((size_t)t * 8 + s) * 2048 + e];
      srt[rk] = ekG[e];
    }
    __syncthreads();
    const double RCLIP = fabs(log(16.0 / 1000.0));
    const float* bbx = p.bbox[l] + (size_t)b * 12 * HW;
    const float* anc = p.anc[l];
    for (int r = tid; r < NPRE; r += 1024) {
      unsigned long long v = srt[r];
      unsigned int key = (unsigned int)(v >> 32);
      double* SB = p.selBoxes + ((size_t)t * NPRE + r) * 4;
      if (key == 0u) {
        SB[0] = 0.0; SB[1] = 0.0; SB[2] = 0.0; SB[3] = 0.0;
        p.selScores[(size_t)t * NPRE + r] = -1.0;
      } else {
        unsigned int idx = ~(unsigned int)(v & 0xFFFFFFFFull);
        int a = (int)(idx % 3u);
        int hw = (int)(idx / 3u);
        double d0 = (double)bbx[(a * 4 + 0) * HW + hw];
        double d1 = (double)bbx[(a * 4 + 1) * HW + hw];
        double d2 = (double)bbx[(a * 4 + 2) * HW + hw];
        double d3 = (double)bbx[(a * 4 + 3) * HW + hw];
        double a0 = (double)anc[(size_t)idx * 4 + 0];
        double a1 = (double)anc[(size_t)idx * 4 + 1];
        double a2 = (double)anc[(size_t)idx * 4 + 2];
        double a3 = (double)anc[(size_t)idx * 4 + 3];
        double dw = fmin(fmax(d2, -RCLIP), RCLIP);
        double dh = fmin(fmax(d3, -RCLIP), RCLIP);
        double pw = a2 - a0, ph = a3 - a1;
        double px = (a0 + a2) * 0.5, py = (a1 + a3) * 0.5;
        double gw = pw * exp(dw), gh = ph * exp(dh);
        double gx = px + pw * d0, gy = py + ph * d1;
        double x1 = fmin(fmax(gx - 0.5 * gw, 0.0), 1344.0);
        double y1 = fmin(fmax(gy - 0.5 * gh, 0.0), 800.0);
        double x2 = fmin(fmax(gx + 0.5 * gw, 0.0), 1344.0);
        double y2 = fmin(fmax(gy + 0.5 * gh, 0.0), 800.0);
        SB[0] = x1; SB[1] = y1; SB[2] = x2; SB[3] = y2;
        float f = unflipf_dev(key);
        p.selScores[(size_t)t * NPRE + r] = 1.0 / (1.0 + exp(-(double)f));
      }
    }
  }
  gbar(p.bar, 6);

  // ---------------- P8: IoU mask (250 blocks, 10 compute waves) -------------
  if (bx < 250) {
    int t = bx / 25;
    int q = bx % 25;
    float* X1 = (float*)SMEM8;
    float* Y1 = X1 + 2048;
    float* X2 = X1 + 4096;
    float* Y2 = X1 + 6144;
    float* AR = X1 + 8192;
    const double* SB = p.selBoxes + (size_t)t * NPRE * 4;
    for (int i = tid; i < 2048; i += 1024) {
      float x1 = 0.f, y1 = 0.f, x2 = 0.f, y2 = 0.f;
      if (i < NPRE) {
        x1 = (float)SB[i * 4 + 0]; y1 = (float)SB[i * 4 + 1];
        x2 = (float)SB[i * 4 + 2]; y2 = (float)SB[i * 4 + 3];
      }
      X1[i] = x1; Y1[i] = y1; X2[i] = x2; Y2[i] = y2;
      AR[i] = (x2 - x1) * (y2 - y1);
    }
    __syncthreads();
    if (tid < 640) {
      int g = q + 25 * wave;  // [0,250)
      int i0 = g * 8;
      float x1i[8], y1i[8], x2i[8], y2i[8], ai[8];
#pragma unroll
      for (int r = 0; r < 8; r++) {
        int i = i0 + r;
        x1i[r] = X1[i]; y1i[r] = Y1[i]; x2i[r] = X2[i]; y2i[r] = Y2[i];
        ai[r] = AR[i];
      }
      int c0 = i0 >> 6;
      int j0 = c0 * 64 + lane;
      float cx1 = X1[j0], cy1 = Y1[j0], cx2 = X2[j0], cy2 = Y2[j0],
            car = AR[j0];
      for (int k = c0; k < 32; k++) {
        float nx1 = 0.f, ny1 = 0.f, nx2 = 0.f, ny2 = 0.f, nar = 0.f;
        if (k + 1 < 32) {
          int jn = (k + 1) * 64 + lane;
          nx1 = X1[jn]; ny1 = Y1[jn]; nx2 = X2[jn]; ny2 = Y2[jn];
          nar = AR[jn];
        }
        int j = k * 64 + lane;
        bool jin = j < NPRE;
        bool pred[8], need[8];
        bool needAny = false;
#pragma unroll
        for (int r = 0; r < 8; r++) {
          int i = i0 + r;
          bool valid = jin && (j > i);
          float lx = fmaxf(x1i[r], cx1), ly = fmaxf(y1i[r], cy1);
          float rx = fminf(x2i[r], cx2), ry = fminf(y2i[r], cy2);
          float w = fmaxf(rx - lx, 0.0f), h = fmaxf(ry - ly, 0.0f);
          float inter = w * h;
          float uni = fmaxf(ai[r] + car - inter, 1e-6f);
          float diff = inter - 0.7f * uni;
          pred[r] = valid && (diff > 0.0f);
          need[r] = valid && (fabsf(diff) <= 4.0f + 1e-5f * uni);
          needAny |= need[r];
        }
        if (__any(needAny)) {
#pragma unroll
          for (int r = 0; r < 8; r++) {
            if (need[r]) {
              int i = i0 + r;
              double a0 = SB[i * 4 + 0], b0 = SB[i * 4 + 1];
              double a2 = SB[i * 4 + 2], b2 = SB[i * 4 + 3];
              double c0d = SB[j * 4 + 0], d0 = SB[j * 4 + 1];
              double c2 = SB[j * 4 + 2], d2 = SB[j * 4 + 3];
              double dai = (a2 - a0) * (b2 - b0);
              double daj = (c2 - c0d) * (d2 - d0);
              double lxd = fmax(a0, c0d), lyd = fmax(b0, d0);
              double rxd = fmin(a2, c2), ryd = fmin(b2, d2);
              double wd = fmax(rxd - lxd, 0.0), hd = fmax(ryd - lyd, 0.0);
              double interd = wd * hd;
              double unid = fmax(dai + daj - interd, 1e-6);
              pred[r] = (interd / unid) > 0.7;
            }
          }
        }
#pragma unroll
        for (int r = 0; r < 8; r++) {
          unsigned long long word = __ballot(pred[r]);
          if (lane == 0) p.mask[((size_t)t * NPRE + i0 + r) * 32 + k] = word;
        }
        cx1 = nx1; cy1 = ny1; cx2 = nx2; cy2 = ny2; car = nar;
      }
    }
  }
  gbar(p.bar, 7);

  // ---------------- P9: greedy NMS + fused re-rank (10 blocks) --------------
  if (bx < 10) {
    int t = bx;
    unsigned long long* ring = SMEM8;  // RING*1024 = 6144 u64
    volatile int* rdy = g_ready;
    volatile int* cons = &g_cons;
    const unsigned long long* MK = p.mask + (size_t)t * NPRE * 32;
    for (int i = tid; i < GRP_N; i += 1024) g_ready[i] = 0;
    if (tid == 0) g_cons = 0;
    __syncthreads();

    if (wave >= 1 && wave <= 3) {
      // producers (3)
      for (int g = wave - 1; g < GRP_N; g += 3) {
        while (g - *cons >= RING) __builtin_amdgcn_s_sleep(1);
        unsigned long long v[16];
#pragma unroll
        for (int k = 0; k < 16; k++) {
          int idx = k * 64 + lane;
          int row = g * 32 + (idx >> 5);
          v[k] = (row < NPRE) ? MK[(size_t)row * 32 + (idx & 31)] : 0ull;
        }
        int slot = g % RING;
#pragma unroll
        for (int k = 0; k < 16; k++)
          ring[slot * 1024 + k * 64 + lane] = v[k];
        __threadfence_block();
        if (lane == 0) rdy[g] = 1;
      }
    } else if (wave == 0) {
      // consumer
      unsigned long long supp = 0ull, keep = 0ull;
      auto doGroup = [&](int g, int base) {
        while (rdy[g] == 0) { }
        __threadfence_block();
        int slot = g % RING;
        int c = g >> 1;
        unsigned long long rv[32];
#pragma unroll
        for (int r = 0; r < 32; r++)
          rv[r] = ring[slot * 1024 + r * 32 + (lane & 31)];
        unsigned int sh = (unsigned int)(supp >> base);
        unsigned int s32 =
            (unsigned int)__builtin_amdgcn_readlane((int)sh, c);
        unsigned int kg = 0;
#pragma unroll
        for (int r = 0; r < 32; r++) {
          unsigned int rvh = (unsigned int)(rv[r] >> base);
          bool kp = (s32 & (1u << r)) == 0u;
          kg |= kp ? (1u << r) : 0u;
          s32 |= kp ? rvh : 0u;
        }
        kg = (unsigned int)__builtin_amdgcn_readlane((int)kg, c);
#pragma unroll
        for (int r = 0; r < 32; r++) {
          if (kg & (1u << r)) supp |= rv[r];
        }
        keep |= (lane == c) ? ((unsigned long long)kg << base) : 0ull;
        __threadfence_block();
        if (lane == 63) *cons = g + 1;
      };
      for (int g = 0; g + 1 < GRP_N; g += 2) {
        doGroup(g, 0);
        doGroup(g + 1, 32);
      }
      doGroup(GRP_N - 1, 0);
      if (lane < 32) g_kw[lane] = keep;
    }
    __syncthreads();

    // fused re-rank (all 16 waves)
    for (int ch = wave; ch < 32; ch += 16) {
      int i = ch * 64 + lane;
      bool inr = i < NPRE;
      bool kb = inr && ((g_kw[ch] >> lane) & 1ull);
      bool A =
          kb && (inr ? (p.selScores[(size_t)t * NPRE + i] > -0.5) : false);
      bool B = inr && !A;
      unsigned long long wa = __ballot(A);
      unsigned long long wb = __ballot(B);
      if (lane == 0) { g_aw[ch] = wa; g_bw[ch] = wb; }
    }
    __syncthreads();
    if (tid == 0) {
      unsigned int ca = 0, cb = 0;
      for (int w = 0; w < 32; w++) {
        g_prefA[w] = ca; ca += __popcll(g_aw[w]);
        g_prefB[w] = cb; cb += __popcll(g_bw[w]);
      }
      g_prefA[32] = ca; g_prefB[32] = cb;
    }
    __syncthreads();
    unsigned int KA = g_prefA[32];
    for (int i = tid; i < NPRE; i += 1024) {
      int w = i >> 6, bpos = i & 63;
      unsigned long long below =
          (bpos == 0) ? 0ull : (~0ull >> (64 - bpos));
      bool kb = (g_kw[w] >> bpos) & 1ull;
      double s = p.selScores[(size_t)t * NPRE + i];
      bool A = kb && (s > -0.5);
      unsigned int slot;
      double outs;
      if (A) {
        slot = g_prefA[w] + (unsigned int)__popcll(g_aw[w] & below);
        outs = s;
      } else {
        slot = KA + g_prefB[w] + (unsigned int)__popcll(g_bw[w] & below);
        outs = -1.0;
      }
      if (slot < NPOST) {
        p.postScores[(size_t)t * NPOST + slot] = outs;
        const double* SB = p.selBoxes + ((size_t)t * NPRE + i) * 4;
        float* PB = p.postBoxes + ((size_t)t * NPOST + slot) * 4;
        PB[0] = (float)SB[0]; PB[1] = (float)SB[1];
        PB[2] = (float)SB[2]; PB[3] = (float)SB[3];
      }
    }
  }
  gbar(p.bar, 8);

  // ---------------- P10: final top-1000 rank (160 blocks) -------------------
  if (bx < 160) {
    int b = bx / 80;
    int rem = bx % 80;
    int s = rem >> 2;
    int ec = rem & 3;
    int j0 = s * 256;
    unsigned long long* kj = SMEM8;  // 256
    if (tid < 256) {
      int e = j0 + tid;
      unsigned long long v = 0ull;
      if (e < 5000) {
        int l = e / 1000, slot = e - l * 1000;
        int t = l * 2 + b;
        v = flip64_dev(p.postScores[(size_t)t * NPOST + slot]);
      }
      kj[tid] = v;
    }
    __syncthreads();
    if (tid < 256) {
      int eidx[5];
      unsigned long long ke[5];
      unsigned int r[5];
#pragma unroll
      for (int k = 0; k < 5; k++) {
        int e = ec * 1280 + k * 256 + tid;
        eidx[k] = (e < 5000) ? e : -1;
        if (eidx[k] >= 0) {
          int l = e / 1000, slot = e - l * 1000;
          int t = l * 2 + b;
          ke[k] = flip64_dev(p.postScores[(size_t)t * NPOST + slot]);
        } else {
          ke[k] = 0ull;
        }
        r[k] = 0;
      }
      for (int j = 0; j < 256; j++) {
        unsigned long long vj = kj[j];
        int jg = j0 + j;
#pragma unroll
        for (int k = 0; k < 5; k++)
          r[k] += (vj > ke[k] || (vj == ke[k] && jg < eidx[k])) ? 1u : 0u;
      }
#pragma unroll
      for (int k = 0; k < 5; k++)
        if (eidx[k] >= 0)
          p.partial[((size_t)b * 20 + s) * 5000 + eidx[k]] = r[k];
    }
  }
  gbar(p.bar, 9);

  // ---------------- P11: reduce ranks, gather output (10 blocks) ------------
  if (bx < 10 && tid < 1000) {
    int b = bx / 5;
    int ch = bx % 5;
    int e = ch * 1000 + tid;
    unsigned int r = 0;
#pragma unroll
    for (int s = 0; s < 20; s++)
      r += p.partial[((size_t)b * 20 + s) * 5000 + e];
    if (r < NPOST) {
      int l = e / 1000, slot = e - l * 1000;
      int t = l * 2 + b;
      const float* PB = p.postBoxes + ((size_t)t * NPOST + slot) * 4;
      float* O = p.out + ((size_t)b * NPOST + r) * 4;
      O[0] = PB[0]; O[1] = PB[1]; O[2] = PB[2]; O[3] = PB[3];
    }
  }
}

extern "C" void kernel_launch(void* const* d_in, const int* in_sizes, int n_in,
                              void* d_out, int out_size, void* d_ws,
                              size_t ws_size, hipStream_t stream) {
  RPNParams p;
  bool interleaved = (n_in >= 2) && (in_sizes[1] == 4 * in_sizes[0]);
  for (int l = 0; l < 5; l++) {
    if (interleaved) {
      p.cls[l]  = (const float*)d_in[3 * l + 0];
      p.bbox[l] = (const float*)d_in[3 * l + 1];
      p.anc[l]  = (const float*)d_in[3 * l + 2];
    } else {
      p.cls[l]  = (const float*)d_in[l];
      p.bbox[l] = (const float*)d_in[5 + l];
      p.anc[l]  = (const float*)d_in[10 + l];
    }
  }
  char* w = (char*)d_ws;
  size_t off = 0;
  auto alloc = [&](size_t bytes) {
    off = (off + 255) & ~(size_t)255;
    void* r = w + off;
    off += bytes;
    return r;
  };
  p.bar       = (unsigned int*)alloc((size_t)10 * 544 * 4);  // 2-level lines
  p.mainCount = (unsigned int*)alloc(10 * 4);
  p.candCount = (unsigned int*)alloc(10 * 4);
  size_t zbytes = off;  // zeroed region: barriers + atomic counters
  p.hist       = (unsigned int*)alloc((size_t)70 * 16384 * 4);
  p.histT      = (unsigned int*)alloc((size_t)8 * 16384 * 4);
  p.Bstar      = (unsigned int*)alloc(10 * 4);
  p.mainEK     = (unsigned long long*)alloc((size_t)10 * 2048 * 8);
  p.candEK     = (unsigned long long*)alloc((size_t)10 * 8192 * 8);
  p.ekG        = (unsigned long long*)alloc((size_t)10 * 2048 * 8);
  p.partialR   = (unsigned int*)alloc((size_t)10 * 8 * 2048 * 4);
  p.selBoxes   = (double*)alloc((size_t)10 * NPRE * 4 * 8);
  p.selScores  = (double*)alloc((size_t)10 * NPRE * 8);
  p.mask       = (unsigned long long*)alloc((size_t)10 * NPRE * 32 * 8);
  p.postScores = (double*)alloc((size_t)10 * NPOST * 8);
  p.postBoxes  = (float*)alloc((size_t)10 * NPOST * 4 * 4);
  p.partial    = (unsigned int*)alloc((size_t)2 * 20 * 5000 * 4);
  p.out = (float*)d_out;
  (void)ws_size; (void)out_size;

  hipMemsetAsync(d_ws, 0, zbytes, stream);
  k_mega<<<dim3(NBLK), dim3(1024), 0, stream>>>(p);
}

// Round 20
// 387.393 us; speedup vs baseline: 3.3754x; 2.6451x over previous
//
#include <hip/hip_runtime.h>
#include <cmath>

// ---------------------------------------------------------------------------
// RPN head post-processing (mmdet GetBboxes-style), exact-semantics HIP port.
//
// R17-R19 PM: mega-fusion with in-kernel device barriers is structurally
// hostile on MI355X -- every correct cross-XCD barrier costs ~70us in cache
// maintenance (L2 wb/inv per wave at agent scope) + cold restarts; three
// barrier designs all landed ~1000us vs the split pipeline's 388us.
// R20: REVERT to the proven R16 split pipeline; fold the 80-byte counter
// memset into k_hist block 0 (removes one graph node). Kernel bodies are
// byte-identical to R16.
// ---------------------------------------------------------------------------

#define NPRE 2000
#define NPOST 1000

static __device__ __forceinline__ unsigned int flipf_dev(float f) {
  unsigned int u = __float_as_uint(f);
  return (u & 0x80000000u) ? ~u : (u | 0x80000000u);
}
static __device__ __forceinline__ float unflipf_dev(unsigned int k) {
  unsigned int u = (k & 0x80000000u) ? (k ^ 0x80000000u) : ~k;
  return __uint_as_float(u);
}
static __device__ __forceinline__ unsigned long long flip64_dev(double d) {
  unsigned long long u = (unsigned long long)__double_as_longlong(d);
  return (u & 0x8000000000000000ull) ? ~u : (u | 0x8000000000000000ull);
}

struct RPNParams {
  const float* cls[5];
  const float* bbox[5];
  const float* anc[5];
  unsigned int* hist;          // [70][16384] private per-block 14-bit hists
  unsigned int* histT;         // [8][16384] per-task reduced hists
  unsigned int* mainCount;     // [10]
  unsigned int* candCount;     // [10]
  unsigned int* Bstar;         // [10]
  unsigned long long* mainEK;  // [10][2048]  packed (key<<32)|~idx
  unsigned long long* candEK;  // [10][8192]
  unsigned long long* ekG;     // [10][2048]  assembled top-2000 (+pads)
  unsigned int* partialR;      // [10][8][2048] sliced ranks
  double* selBoxes;            // [10][2000][4]
  double* selScores;           // [10][2000]
  unsigned long long* mask;    // [10][2000][32]
  double* postScores;          // [10][1000]
  float* postBoxes;            // [10][1000][4]
  unsigned int* partial;       // [2][20][5000]
  float* out;                  // [2][1000][4]
};

__device__ __constant__ int c_NL[5]  = {201600, 50400, 12600, 3150, 819};
__device__ __constant__ int c_HW[5]  = {67200, 16800, 4200, 1050, 273};
// blocks-per-task at 2048 elements/block (levels 0..3 x 2 images) -- compact
__device__ __constant__ int c_BPT[8] = {99, 99, 25, 25, 7, 7, 2, 2};
// blocks-per-task at 8192 elements/block -- hist (total 70)
__device__ __constant__ int c_BPT12[8] = {25, 25, 7, 7, 2, 2, 1, 1};
__device__ __constant__ int c_HSTART[8] = {0, 25, 50, 57, 64, 66, 68, 69};

static __device__ __forceinline__ void map_block(int bx, int& t, int& chunk) {
  int start = 0;
  t = 0;
  for (int k = 0; k < 8; k++) {
    if (bx < start + c_BPT[k]) { t = k; break; }
    start += c_BPT[k];
  }
  chunk = bx - start;
}
static __device__ __forceinline__ void map_block12(int bx, int& t, int& chunk) {
  int start = 0;
  t = 0;
  for (int k = 0; k < 8; k++) {
    if (bx < start + c_BPT12[k]) { t = k; break; }
    start += c_BPT12[k];
  }
  chunk = bx - start;
}

// --- 1. per-block PRIVATE 14-bit histogram (LDS atomics, no global atomics) -
// Block 0 also zeroes the 20 atomic counters (used 2 dispatches later by
// k_compact -- stream order guarantees visibility; removes the memset node).
__global__ __launch_bounds__(1024) void k_hist(RPNParams p) {
  __shared__ unsigned int lh[16384];  // 64 KB
  int t, chunk;
  map_block12(blockIdx.x, t, chunk);
  int l = t >> 1, b = t & 1;
  int N = c_NL[l], HW = c_HW[l];
  const float* cls = p.cls[l] + (size_t)b * 3 * HW;
  int tid = threadIdx.x;
  if (blockIdx.x == 0 && tid < 10) {
    p.mainCount[tid] = 0u;
    p.candCount[tid] = 0u;
  }
  for (int i = tid; i < 16384; i += 1024) lh[i] = 0;
  __syncthreads();
  int base = chunk * 8192 + tid;
#pragma unroll
  for (int k = 0; k < 8; k++) {
    int n = base + k * 1024;
    if (n < N) {
      int a = n % 3, hw = n / 3;
      unsigned int key = flipf_dev(cls[a * HW + hw]);
      atomicAdd(&lh[key >> 18], 1u);
    }
  }
  __syncthreads();
  unsigned int* hout = p.hist + (size_t)blockIdx.x * 16384;
  for (int i = tid; i < 16384; i += 1024) hout[i] = lh[i];
}

// --- 1b. reduce private hists -> per-task hist (128 blocks, 1 bin/thread) ---
__global__ __launch_bounds__(1024) void k_hred(RPNParams p) {
  int t = blockIdx.x >> 4;       // task 0..7
  int slice = blockIdx.x & 15;   // 0..15
  int bin = slice * 1024 + threadIdx.x;
  int start = c_HSTART[t];
  int bpt = c_BPT12[t];
  unsigned int s0 = 0, s1 = 0, s2 = 0, s3 = 0;
  int bb = 0;
  for (; bb + 4 <= bpt; bb += 4) {
    s0 += p.hist[(size_t)(start + bb + 0) * 16384 + bin];
    s1 += p.hist[(size_t)(start + bb + 1) * 16384 + bin];
    s2 += p.hist[(size_t)(start + bb + 2) * 16384 + bin];
    s3 += p.hist[(size_t)(start + bb + 3) * 16384 + bin];
  }
  for (; bb < bpt; bb++) s0 += p.hist[(size_t)(start + bb) * 16384 + bin];
  p.histT[(size_t)t * 16384 + bin] = s0 + s1 + s2 + s3;
}

// --- 2. find threshold bucket B* per task (reads reduced hist) --------------
__global__ __launch_bounds__(1024) void k_find(RPNParams p) {
  int t = blockIdx.x;  // 0..7
  __shared__ unsigned int H[16384];  // 64 KB
  __shared__ unsigned int S[1024];
  __shared__ int gsel;
  __shared__ unsigned int baseAbove;
  int tid = threadIdx.x;  // 1024
  const unsigned int* hT = p.histT + (size_t)t * 16384;
  for (int bin = tid; bin < 16384; bin += 1024) H[bin] = hT[bin];
  __syncthreads();
  {
    unsigned int s = 0;
#pragma unroll
    for (int k = 0; k < 16; k++) s += H[tid * 16 + k];
    S[tid] = s;
  }
  __syncthreads();
  for (int off = 1; off < 1024; off <<= 1) {
    unsigned int add = (tid + off < 1024) ? S[tid + off] : 0u;
    __syncthreads();
    S[tid] += add;
    __syncthreads();
  }
  const unsigned int need = NPRE;
  if (S[tid] >= need && (tid == 1023 || S[tid + 1] < need)) {
    gsel = tid;
    baseAbove = (tid == 1023) ? 0u : S[tid + 1];
  }
  __syncthreads();
  if (tid == 0) {
    int gg = gsel;
    unsigned int c = baseAbove;
    int bstar = gg * 16;
    for (int bb = 15; bb >= 0; bb--) {
      c += H[gg * 16 + bb];
      if (c >= need) { bstar = gg * 16 + bb; break; }
    }
    p.Bstar[t] = (unsigned int)bstar;
  }
}

// --- 3. compaction: above-bucket -> main, == bucket -> cand (14-bit) --------
__global__ void k_compact(RPNParams p) {
  int t, chunk;
  map_block(blockIdx.x, t, chunk);
  int l = t >> 1, b = t & 1;
  int N = c_NL[l], HW = c_HW[l];
  const float* cls = p.cls[l] + (size_t)b * 3 * HW;
  unsigned int Bs = p.Bstar[t];
  int base = chunk * 2048 + threadIdx.x;
  for (int k = 0; k < 2; k++) {
    int n = base + k * 1024;
    if (n < N) {
      int a = n % 3, hw = n / 3;
      unsigned int key = flipf_dev(cls[a * HW + hw]);
      unsigned int hi = key >> 18;
      unsigned long long ek =
          ((unsigned long long)key << 32) | (unsigned int)(~(unsigned int)n);
      if (hi > Bs) {
        unsigned int pos = atomicAdd(&p.mainCount[t], 1u);
        if (pos < 2048u) p.mainEK[(size_t)t * 2048 + pos] = ek;
      } else if (hi == Bs) {
        unsigned int pos = atomicAdd(&p.candCount[t], 1u);
        if (pos < 8192u) p.candEK[(size_t)t * 8192 + pos] = ek;
      }
    }
  }
}

// --- 4a. fill ekG[t][2048]: exact top-2000 keys + pads ----------------------
__global__ void k_fill(RPNParams p) {
  int t = blockIdx.x;  // 0..9
  int l = t >> 1, b = t & 1;
  int N = c_NL[l], HW = c_HW[l];
  int tid = threadIdx.x;  // 256
  unsigned long long* ekG = p.ekG + (size_t)t * 2048;
  if (N >= NPRE) {
    unsigned int cGT = min(p.mainCount[t], 2000u);
    unsigned int nC = min(p.candCount[t], 8192u);
    unsigned int needIn = 2000u - cGT;
    for (unsigned int m = tid; m < cGT; m += 256)
      ekG[m] = p.mainEK[(size_t)t * 2048 + m];
    const unsigned long long* cek = p.candEK + (size_t)t * 8192;
    for (unsigned int e = tid; e < nC; e += 256) {
      unsigned long long ve = cek[e];
      unsigned int r = 0;
      for (unsigned int j = 0; j < nC; j++) r += (cek[j] > ve) ? 1u : 0u;
      if (r < needIn) ekG[cGT + r] = ve;
    }
    for (unsigned int r2 = 2000u + tid; r2 < 2048u; r2 += 256)
      ekG[r2] = (unsigned long long)(unsigned int)(~r2);
  } else {
    // level 4 (N=819): pad path -- key 0 pads below all finite logits
    const float* cls = p.cls[l] + (size_t)b * 3 * HW;
    for (int r = tid; r < 2048; r += 256) {
      if (r < N) {
        int a = r % 3, hw = r / 3;
        unsigned int key = flipf_dev(cls[a * HW + hw]);
        ekG[r] = ((unsigned long long)key << 32) |
                 (unsigned int)(~(unsigned int)r);
      } else {
        ekG[r] = (unsigned long long)(unsigned int)(~(unsigned int)r);
      }
    }
  }
}

// --- 4b. sliced counting-rank: 8 slices x 10 tasks --------------------------
__global__ void k_rank(RPNParams p) {
  int t = blockIdx.x >> 3;
  int s = blockIdx.x & 7;
  int tid = threadIdx.x;  // 256
  __shared__ unsigned long long sl[256];
  const unsigned long long* ekG = p.ekG + (size_t)t * 2048;
  sl[tid] = ekG[s * 256 + tid];
  __syncthreads();
  unsigned long long ve[8];
  unsigned int r[8];
#pragma unroll
  for (int k = 0; k < 8; k++) {
    ve[k] = ekG[k * 256 + tid];
    r[k] = 0;
  }
  for (int j = 0; j < 256; j++) {
    unsigned long long vj = sl[j];
#pragma unroll
    for (int k = 0; k < 8; k++) r[k] += (vj > ve[k]) ? 1u : 0u;
  }
  unsigned int* out = p.partialR + ((size_t)t * 8 + s) * 2048;
#pragma unroll
  for (int k = 0; k < 8; k++) out[k * 256 + tid] = r[k];
}

// --- 4c. scatter by total rank + fp64 decode --------------------------------
__global__ void k_scatter(RPNParams p) {
  int t = blockIdx.x;  // 0..9
  int l = t >> 1, b = t & 1;
  int HW = c_HW[l];
  int tid = threadIdx.x;  // 1024
  __shared__ unsigned long long srt[2048];
  const unsigned long long* ekG = p.ekG + (size_t)t * 2048;
  for (int e = tid; e < 2048; e += 1024) {
    unsigned int rk = 0;
#pragma unroll
    for (int s = 0; s < 8; s++)
      rk += p.partialR[((size_t)t * 8 + s) * 2048 + e];
    srt[rk] = ekG[e];
  }
  __syncthreads();

  const double RCLIP = fabs(log(16.0 / 1000.0));  // mmdet wh_ratio_clip
  const float* bbx = p.bbox[l] + (size_t)b * 12 * HW;
  const float* anc = p.anc[l];
  for (int r = tid; r < NPRE; r += 1024) {
    unsigned long long v = srt[r];
    unsigned int key = (unsigned int)(v >> 32);
    double* SB = p.selBoxes + ((size_t)t * NPRE + r) * 4;
    if (key == 0u) {  // pad: zero anchors/deltas -> zero box, score -1
      SB[0] = 0.0; SB[1] = 0.0; SB[2] = 0.0; SB[3] = 0.0;
      p.selScores[(size_t)t * NPRE + r] = -1.0;
    } else {
      unsigned int idx = ~(unsigned int)(v & 0xFFFFFFFFull);
      int a = (int)(idx % 3u);
      int hw = (int)(idx / 3u);
      double d0 = (double)bbx[(a * 4 + 0) * HW + hw];
      double d1 = (double)bbx[(a * 4 + 1) * HW + hw];
      double d2 = (double)bbx[(a * 4 + 2) * HW + hw];
      double d3 = (double)bbx[(a * 4 + 3) * HW + hw];
      double a0 = (double)anc[(size_t)idx * 4 + 0];
      double a1 = (double)anc[(size_t)idx * 4 + 1];
      double a2 = (double)anc[(size_t)idx * 4 + 2];
      double a3 = (double)anc[(size_t)idx * 4 + 3];
      double dw = fmin(fmax(d2, -RCLIP), RCLIP);
      double dh = fmin(fmax(d3, -RCLIP), RCLIP);
      double pw = a2 - a0, ph = a3 - a1;
      double px = (a0 + a2) * 0.5, py = (a1 + a3) * 0.5;
      double gw = pw * exp(dw), gh = ph * exp(dh);
      double gx = px + pw * d0, gy = py + ph * d1;
      double x1 = fmin(fmax(gx - 0.5 * gw, 0.0), 1344.0);
      double y1 = fmin(fmax(gy - 0.5 * gh, 0.0), 800.0);
      double x2 = fmin(fmax(gx + 0.5 * gw, 0.0), 1344.0);
      double y2 = fmin(fmax(gy + 0.5 * gh, 0.0), 800.0);
      SB[0] = x1; SB[1] = y1; SB[2] = x2; SB[3] = y2;
      float f = unflipf_dev(key);
      p.selScores[(size_t)t * NPRE + r] = 1.0 / (1.0 + exp(-(double)f));
    }
  }
}

// --- 5. IoU -> suppression bitmask. 8 rows share each column load. ----------
__global__ __launch_bounds__(640) void k_iou(RPNParams p) {
  int bx = blockIdx.x;
  int t = bx / 25;
  int q = bx % 25;
  __shared__ float X1[2048], Y1[2048], X2[2048], Y2[2048], AR[2048];
  const double* SB = p.selBoxes + (size_t)t * NPRE * 4;
  for (int i = threadIdx.x; i < 2048; i += 640) {
    float x1 = 0.f, y1 = 0.f, x2 = 0.f, y2 = 0.f;
    if (i < NPRE) {
      x1 = (float)SB[i * 4 + 0]; y1 = (float)SB[i * 4 + 1];
      x2 = (float)SB[i * 4 + 2]; y2 = (float)SB[i * 4 + 3];
    }
    X1[i] = x1; Y1[i] = y1; X2[i] = x2; Y2[i] = y2;
    AR[i] = (x2 - x1) * (y2 - y1);
  }
  __syncthreads();
  int wave = threadIdx.x >> 6, lane = threadIdx.x & 63;
  int g = q + 25 * wave;  // [0,250)
  int i0 = g * 8;
  float x1i[8], y1i[8], x2i[8], y2i[8], ai[8];
#pragma unroll
  for (int r = 0; r < 8; r++) {
    int i = i0 + r;
    x1i[r] = X1[i]; y1i[r] = Y1[i]; x2i[r] = X2[i]; y2i[r] = Y2[i];
    ai[r] = AR[i];
  }
  int c0 = i0 >> 6;
  int j0 = c0 * 64 + lane;
  float cx1 = X1[j0], cy1 = Y1[j0], cx2 = X2[j0], cy2 = Y2[j0], car = AR[j0];
  for (int k = c0; k < 32; k++) {
    float nx1 = 0.f, ny1 = 0.f, nx2 = 0.f, ny2 = 0.f, nar = 0.f;
    if (k + 1 < 32) {  // prefetch next column word
      int jn = (k + 1) * 64 + lane;
      nx1 = X1[jn]; ny1 = Y1[jn]; nx2 = X2[jn]; ny2 = Y2[jn];
      nar = AR[jn];
    }
    int j = k * 64 + lane;
    bool jin = j < NPRE;
    bool pred[8], need[8];
    bool needAny = false;
#pragma unroll
    for (int r = 0; r < 8; r++) {
      int i = i0 + r;
      bool valid = jin && (j > i);
      float lx = fmaxf(x1i[r], cx1), ly = fmaxf(y1i[r], cy1);
      float rx = fminf(x2i[r], cx2), ry = fminf(y2i[r], cy2);
      float w = fmaxf(rx - lx, 0.0f), h = fmaxf(ry - ly, 0.0f);
      float inter = w * h;
      float uni = fmaxf(ai[r] + car - inter, 1e-6f);
      float diff = inter - 0.7f * uni;
      pred[r] = valid && (diff > 0.0f);
      need[r] = valid && (fabsf(diff) <= 4.0f + 1e-5f * uni);
      needAny |= need[r];
    }
    if (__any(needAny)) {  // rare: exact fp64 near the 0.7 boundary
#pragma unroll
      for (int r = 0; r < 8; r++) {
        if (need[r]) {
          int i = i0 + r;
          double a0 = SB[i * 4 + 0], b0 = SB[i * 4 + 1];
          double a2 = SB[i * 4 + 2], b2 = SB[i * 4 + 3];
          double c0d = SB[j * 4 + 0], d0 = SB[j * 4 + 1];
          double c2 = SB[j * 4 + 2], d2 = SB[j * 4 + 3];
          double dai = (a2 - a0) * (b2 - b0);
          double daj = (c2 - c0d) * (d2 - d0);
          double lxd = fmax(a0, c0d), lyd = fmax(b0, d0);
          double rxd = fmin(a2, c2), ryd = fmin(b2, d2);
          double wd = fmax(rxd - lxd, 0.0), hd = fmax(ryd - lyd, 0.0);
          double interd = wd * hd;
          double unid = fmax(dai + daj - interd, 1e-6);
          pred[r] = (interd / unid) > 0.7;
        }
      }
    }
#pragma unroll
    for (int r = 0; r < 8; r++) {
      unsigned long long word = __ballot(pred[r]);
      if (lane == 0) p.mask[((size_t)t * NPRE + i0 + r) * 32 + k] = word;
    }
    cx1 = nx1; cy1 = ny1; cx2 = nx2; cy2 = ny2; car = nar;
  }
}

// --- 6. greedy NMS: 1 consumer + 3 producer waves (one per SIMD) ------------
#define GRP_N 63
#define RING 6
__global__ __launch_bounds__(256) void k_greedy(RPNParams p) {
  int t = blockIdx.x;
  int tid = threadIdx.x;
  __shared__ unsigned long long ring[RING * 1024];  // 48 KB
  __shared__ int ready[GRP_N];
  __shared__ int cons_s;
  __shared__ unsigned long long kw[32], aw[32], bw[32];
  __shared__ unsigned int prefA[33], prefB[33];
  volatile int* rdy = ready;
  volatile int* cons = &cons_s;
  const unsigned long long* MK = p.mask + (size_t)t * NPRE * 32;
  for (int i = tid; i < GRP_N; i += 256) ready[i] = 0;
  if (tid == 0) cons_s = 0;
  __syncthreads();

  int wave = tid >> 6, lane = tid & 63;
  if (wave >= 1) {
    // ---------------- producer waves (3, each alone on a SIMD) -------------
    for (int g = wave - 1; g < GRP_N; g += 3) {
      while (g - *cons >= RING) __builtin_amdgcn_s_sleep(1);
      unsigned long long v[16];
#pragma unroll
      for (int k = 0; k < 16; k++) {
        int idx = k * 64 + lane;           // 0..1023
        int row = g * 32 + (idx >> 5);
        v[k] = (row < NPRE) ? MK[(size_t)row * 32 + (idx & 31)] : 0ull;
      }
      int slot = g % RING;
#pragma unroll
      for (int k = 0; k < 16; k++)
        ring[slot * 1024 + k * 64 + lane] = v[k];
      __threadfence_block();  // data visible before publish
      if (lane == 0) rdy[g] = 1;
    }
  } else {
    // ---------------- consumer wave (alone on its SIMD) --------------------
    unsigned long long supp = 0ull, keep = 0ull;  // lane j<32: word j
    auto doGroup = [&](int g, int base) {
      while (rdy[g] == 0) { }  // busy-poll
      __threadfence_block();
      int slot = g % RING;
      int c = g >> 1;  // owner chunk (uniform scalar)
      unsigned long long rv[32];
#pragma unroll
      for (int r = 0; r < 32; r++)
        rv[r] = ring[slot * 1024 + r * 32 + (lane & 31)];
      unsigned int sh = (unsigned int)(supp >> base);  // base is literal
      unsigned int s32 = (unsigned int)__builtin_amdgcn_readlane((int)sh, c);
      unsigned int kg = 0;
#pragma unroll
      for (int r = 0; r < 32; r++) {
        unsigned int rvh = (unsigned int)(rv[r] >> base);  // reg-select
        bool kp = (s32 & (1u << r)) == 0u;
        kg |= kp ? (1u << r) : 0u;
        s32 |= kp ? rvh : 0u;
      }
      kg = (unsigned int)__builtin_amdgcn_readlane((int)kg, c);  // SGPR
      // apply: scalar-uniform branch per kept row -> single v_or_b64
#pragma unroll
      for (int r = 0; r < 32; r++) {
        if (kg & (1u << r)) supp |= rv[r];
      }
      keep |= (lane == c) ? ((unsigned long long)kg << base) : 0ull;
      __threadfence_block();  // rv reads retired before freeing slot
      if (lane == 63) *cons = g + 1;
    };
    for (int g = 0; g + 1 < GRP_N; g += 2) {
      doGroup(g, 0);
      doGroup(g + 1, 32);
    }
    doGroup(GRP_N - 1, 0);  // group 62 (even -> base 0)
    if (lane < 32) kw[lane] = keep;
  }
  __syncthreads();

  // ---------------- fused re-rank (all 4 waves) ----------------
  for (int ch = wave; ch < 32; ch += 4) {
    int i = ch * 64 + lane;
    bool inr = i < NPRE;
    bool kb = inr && ((kw[ch] >> lane) & 1ull);
    bool A = kb && (inr ? (p.selScores[(size_t)t * NPRE + i] > -0.5) : false);
    bool B = inr && !A;
    unsigned long long wa = __ballot(A);
    unsigned long long wb = __ballot(B);
    if (lane == 0) { aw[ch] = wa; bw[ch] = wb; }
  }
  __syncthreads();
  if (tid == 0) {
    unsigned int ca = 0, cb = 0;
    for (int w = 0; w < 32; w++) {
      prefA[w] = ca; ca += __popcll(aw[w]);
      prefB[w] = cb; cb += __popcll(bw[w]);
    }
    prefA[32] = ca; prefB[32] = cb;
  }
  __syncthreads();
  unsigned int KA = prefA[32];
  for (int i = tid; i < NPRE; i += 256) {
    int w = i >> 6, bpos = i & 63;
    unsigned long long below = (bpos == 0) ? 0ull : (~0ull >> (64 - bpos));
    bool kb = (kw[w] >> bpos) & 1ull;
    double s = p.selScores[(size_t)t * NPRE + i];
    bool A = kb && (s > -0.5);
    unsigned int slot;
    double outs;
    if (A) {
      slot = prefA[w] + (unsigned int)__popcll(aw[w] & below);
      outs = s;
    } else {
      slot = KA + prefB[w] + (unsigned int)__popcll(bw[w] & below);
      outs = -1.0;
    }
    if (slot < NPOST) {
      p.postScores[(size_t)t * NPOST + slot] = outs;
      const double* SB = p.selBoxes + ((size_t)t * NPRE + i) * 4;
      float* PB = p.postBoxes + ((size_t)t * NPOST + slot) * 4;
      PB[0] = (float)SB[0]; PB[1] = (float)SB[1];
      PB[2] = (float)SB[2]; PB[3] = (float)SB[3];
    }
  }
}

// --- 8a. final cross-level top-1000: k_rank-shaped counting-rank ------------
__global__ void k_finalA(RPNParams p) {
  int bx = blockIdx.x;
  int b = bx / 80;        // image 0..1
  int rem = bx % 80;
  int s = rem >> 2;       // j-slice 0..19
  int ec = rem & 3;       // e-chunk 0..3
  int j0 = s * 256;
  __shared__ unsigned long long kj[256];
  int tid = threadIdx.x;  // 256
  {
    int e = j0 + tid;
    unsigned long long v = 0ull;
    if (e < 5000) {
      int l = e / 1000, slot = e - l * 1000;
      int t = l * 2 + b;
      v = flip64_dev(p.postScores[(size_t)t * NPOST + slot]);
    }
    kj[tid] = v;
  }
  __syncthreads();
  int eidx[5];
  unsigned long long ke[5];
  unsigned int r[5];
#pragma unroll
  for (int k = 0; k < 5; k++) {
    int e = ec * 1280 + k * 256 + tid;
    eidx[k] = (e < 5000) ? e : -1;
    if (eidx[k] >= 0) {
      int l = e / 1000, slot = e - l * 1000;
      int t = l * 2 + b;
      ke[k] = flip64_dev(p.postScores[(size_t)t * NPOST + slot]);
    } else {
      ke[k] = 0ull;
    }
    r[k] = 0;
  }
  for (int j = 0; j < 256; j++) {
    unsigned long long vj = kj[j];
    int jg = j0 + j;
#pragma unroll
    for (int k = 0; k < 5; k++)
      r[k] += (vj > ke[k] || (vj == ke[k] && jg < eidx[k])) ? 1u : 0u;
  }
#pragma unroll
  for (int k = 0; k < 5; k++)
    if (eidx[k] >= 0)
      p.partial[((size_t)b * 20 + s) * 5000 + eidx[k]] = r[k];
}

// --- 8b. reduce ranks (20 slices), gather output boxes ----------------------
__global__ void k_finalB(RPNParams p) {
  int b = blockIdx.x / 5;
  int ch = blockIdx.x % 5;
  int tid = threadIdx.x;  // 1024
  if (tid < 1000) {
    int e = ch * 1000 + tid;
    unsigned int r = 0;
#pragma unroll
    for (int s = 0; s < 20; s++)
      r += p.partial[((size_t)b * 20 + s) * 5000 + e];
    if (r < NPOST) {
      int l = e / 1000, slot = e - l * 1000;
      int t = l * 2 + b;
      const float* PB = p.postBoxes + ((size_t)t * NPOST + slot) * 4;
      float* O = p.out + ((size_t)b * NPOST + r) * 4;
      O[0] = PB[0]; O[1] = PB[1]; O[2] = PB[2]; O[3] = PB[3];
    }
  }
}

extern "C" void kernel_launch(void* const* d_in, const int* in_sizes, int n_in,
                              void* d_out, int out_size, void* d_ws,
                              size_t ws_size, hipStream_t stream) {
  RPNParams p;
  bool interleaved = (n_in >= 2) && (in_sizes[1] == 4 * in_sizes[0]);
  for (int l = 0; l < 5; l++) {
    if (interleaved) {
      p.cls[l]  = (const float*)d_in[3 * l + 0];
      p.bbox[l] = (const float*)d_in[3 * l + 1];
      p.anc[l]  = (const float*)d_in[3 * l + 2];
    } else {
      p.cls[l]  = (const float*)d_in[l];
      p.bbox[l] = (const float*)d_in[5 + l];
      p.anc[l]  = (const float*)d_in[10 + l];
    }
  }
  char* w = (char*)d_ws;
  size_t off = 0;
  auto alloc = [&](size_t bytes) {
    off = (off + 255) & ~(size_t)255;
    void* r = w + off;
    off += bytes;
    return r;
  };
  p.mainCount = (unsigned int*)alloc(10 * 4);  // zeroed by k_hist block 0
  p.candCount = (unsigned int*)alloc(10 * 4);
  p.hist       = (unsigned int*)alloc((size_t)70 * 16384 * 4);
  p.histT      = (unsigned int*)alloc((size_t)8 * 16384 * 4);
  p.Bstar      = (unsigned int*)alloc(10 * 4);
  p.mainEK     = (unsigned long long*)alloc((size_t)10 * 2048 * 8);
  p.candEK     = (unsigned long long*)alloc((size_t)10 * 8192 * 8);
  p.ekG        = (unsigned long long*)alloc((size_t)10 * 2048 * 8);
  p.partialR   = (unsigned int*)alloc((size_t)10 * 8 * 2048 * 4);
  p.selBoxes   = (double*)alloc((size_t)10 * NPRE * 4 * 8);
  p.selScores  = (double*)alloc((size_t)10 * NPRE * 8);
  p.mask       = (unsigned long long*)alloc((size_t)10 * NPRE * 32 * 8);
  p.postScores = (double*)alloc((size_t)10 * NPOST * 8);
  p.postBoxes  = (float*)alloc((size_t)10 * NPOST * 4 * 4);
  p.partial    = (unsigned int*)alloc((size_t)2 * 20 * 5000 * 4);
  p.out = (float*)d_out;
  (void)ws_size; (void)out_size;

  k_hist<<<dim3(70), dim3(1024), 0, stream>>>(p);
  k_hred<<<dim3(128), dim3(1024), 0, stream>>>(p);
  k_find<<<dim3(8), dim3(1024), 0, stream>>>(p);
  k_compact<<<dim3(266), dim3(1024), 0, stream>>>(p);
  k_fill<<<dim3(10), dim3(256), 0, stream>>>(p);
  k_rank<<<dim3(80), dim3(256), 0, stream>>>(p);
  k_scatter<<<dim3(10), dim3(1024), 0, stream>>>(p);
  k_iou<<<dim3(250), dim3(640), 0, stream>>>(p);
  k_greedy<<<dim3(10), dim3(256), 0, stream>>>(p);
  k_finalA<<<dim3(160), dim3(256), 0, stream>>>(p);
  k_finalB<<<dim3(10), dim3(1024), 0, stream>>>(p);
}